// Round 14
// baseline (523.577 us; speedup 1.0000x reference)
//
#include <hip/hip_runtime.h>
#include <hip/hip_bf16.h>

#define NN 50000
#define NE 800000
#define FD 80
#define NGR 1024
#define NF 9

// bucketed CSR sort (atomic-free counting sort)
#define BSH 6
#define NBUCK ((NN + 63) >> 6)     // 782 node-buckets of 64
#define CSH 12
#define NCH ((NE + 4095) >> 12)    // 196 edge-chunks of 4096
#define BCAP 2048

using bf16 = __hip_bfloat16;
typedef __attribute__((ext_vector_type(8))) short bf16x8;
typedef __attribute__((ext_vector_type(4))) float f32x4;

static __device__ __forceinline__ float b2f(bf16 v){ return __bfloat162float(v); }
static __device__ __forceinline__ bf16 f2b(float v){ return __float2bfloat16(v); }
static __device__ __forceinline__ float rdw(const void* p, int i, int fl){
  return fl ? ((const float*)p)[i] : b2f(((const bf16*)p)[i]);
}
static __device__ __forceinline__ unsigned pk(float a, float b){
  bf16 x = f2b(a), y = f2b(b);
  return (unsigned)*(unsigned short*)&x | ((unsigned)*(unsigned short*)&y << 16);
}
// 8B-granule LDS access (strides are 8B- but not 16B-aligned)
static __device__ __forceinline__ bf16x8 ldsld8(const short* p){
  union { bf16x8 v; uint2 u[2]; } r;
  r.u[0] = *(const uint2*)(p);
  r.u[1] = *(const uint2*)(p + 4);
  return r.v;
}
static __device__ __forceinline__ void ldsst16(short* p, uint4 v){
  *(uint2*)(p)     = make_uint2(v.x, v.y);
  *(uint2*)(p + 4) = make_uint2(v.z, v.w);
}

// ------------------------------------------------------------------ utility
__global__ void k_zero(int* __restrict__ p, int n){
  int t = blockIdx.x*256 + threadIdx.x;
  if (t < n) p[t] = 0;
}

__global__ void k_probe(const void* __restrict__ emb, int* __restrict__ flag){
  int t = blockIdx.x*256 + threadIdx.x;
  float v = b2f(((const bf16*)emb)[t]);
  if (!(fabsf(v) < 1e4f)) atomicOr(flag, 1);
}

// ------------------------------------------------------------------ fused weight prep
// Bt1 in K-step-major FRAGMENT-TILED layout: element (c,k) at
// ks*160*32 + c*32 + (k&31) -> one wave's MFMA B-frag load is a contiguous
// 1KB segment (direct-global, no LDS staging).
__global__ __launch_bounds__(256) void k_prep_all(
    const void* __restrict__ preW, const void* __restrict__ preb,
    const void* __restrict__ postW, const void* __restrict__ postb,
    const void* __restrict__ linW, const void* __restrict__ linb,
    const void* __restrict__ bng, const void* __restrict__ bnb,
    const void* __restrict__ bnm, const void* __restrict__ bnv,
    const int* __restrict__ flag,
    bf16* __restrict__ pwb, bf16* __restrict__ Btl, bf16* __restrict__ Bt1,
    float* __restrict__ bias1, float* __restrict__ bias2)
{
  int fl = flag[0];
  int b = blockIdx.x;
  if (b < 1300){
    int t = b*256 + threadIdx.x;
    pwb[t] = f2b(rdw(postW, t, fl));
  } else if (b < 1420){
    int t = (b - 1300)*256 + threadIdx.x;
    int j = t % 96, c = (t/96) % 80, i = t/(96*80);
    float v = 0.f;
    if (j < 80){
      float gs = rdw(bng, i*80 + c, fl) * rsqrtf(rdw(bnv, i*80 + c, fl) + 1e-5f);
      v = rdw(linW, i*6400 + j*80 + c, fl) * gs;
    }
    Btl[t] = f2b(v);
  } else if (b < 1660){
    int t = (b - 1420)*256 + threadIdx.x;
    int k = t % 96, c = (t/96) % 160, i = t/(96*160);
    float v = 0.f;
    if (k < 80)
      v = (c < 80) ? rdw(preW, (i*160 + k)*80 + c, fl)
                   : rdw(preW, (i*160 + 80 + k)*80 + (c - 80), fl);
    int of = ((k >> 5)*160 + c)*32 + (k & 31);
    Bt1[i*15360 + of] = f2b(v);
    if (k == 0) bias1[i*160 + c] = (c < 80) ? rdw(preb, i*80 + c, fl) : 0.f;
  } else {
    int t = (b - 1660)*256 + threadIdx.x;
    if (t >= 4*80) return;
    int i = t / 80, f = t - i*80;
    float s = 0.f;
    for (int j = 0; j < 80; j++)
      s += rdw(postb, i*80 + j, fl) * rdw(linW, (i*80 + j)*80 + f, fl);
    s += rdw(linb, t, fl);
    float gs = rdw(bng, t, fl) * rsqrtf(rdw(bnv, t, fl) + 1e-5f);
    bias2[t] = (s - rdw(bnm, t, fl)) * gs + rdw(bnb, t, fl);
  }
}

// Bt2 in fragment-tiled layout: element (c,k) at ks*240*32 + c*32 + (k&31).
__global__ void k_prep_Bt2(const float* __restrict__ Wf, bf16* __restrict__ Bt2){
  int t = blockIdx.x*256 + threadIdx.x;
  if (t >= 4*240*416) return;
  int k = t % 416;
  int c = (t/416) % 240;
  int i = t/(416*240);
  float v = 0.f;
  if (k < 400){
    int blk = c/80, f = c - blk*80;
    if (blk == 0) v = Wf[(i*1040 + k)*80 + f];
    else if (k >= 80){
      int row = (blk == 1 ? 400 : 720) + (k - 80);
      v = Wf[(i*1040 + row)*80 + f];
    }
  }
  int of = (k >> 5)*7680 + c*32 + (k & 31);
  Bt2[i*99840 + of] = f2b(v);
}

// ------------------------------------------------------------------ graph prep
__global__ void k_atom(const int* __restrict__ x, const void* __restrict__ emb,
                       const int* __restrict__ flag, float* __restrict__ h){
  int fl = flag[0];
  int gid = blockIdx.x*256 + threadIdx.x;
  if (gid >= NN*10) return;
  int n = gid / 10, fb = gid - n*10;
  int f0 = fb*8;
  int xr[NF];
  #pragma unroll
  for (int c = 0; c < NF; c++) xr[c] = x[n*NF + c];
  float s[8] = {0.f,0.f,0.f,0.f,0.f,0.f,0.f,0.f};
  if (fl){
    #pragma unroll
    for (int c = 0; c < NF; c++){
      const float* ep = (const float*)emb + (c*119 + xr[c])*80 + f0;
      float4 a = *(const float4*)ep, b = *(const float4*)(ep + 4);
      s[0]+=a.x; s[1]+=a.y; s[2]+=a.z; s[3]+=a.w;
      s[4]+=b.x; s[5]+=b.y; s[6]+=b.z; s[7]+=b.w;
    }
  } else {
    #pragma unroll
    for (int c = 0; c < NF; c++){
      const bf16* ep = (const bf16*)emb + (c*119 + xr[c])*80 + f0;
      uint4 u = *(const uint4*)ep;
      s[0]+=__uint_as_float(u.x<<16); s[1]+=__uint_as_float(u.x&0xffff0000u);
      s[2]+=__uint_as_float(u.y<<16); s[3]+=__uint_as_float(u.y&0xffff0000u);
      s[4]+=__uint_as_float(u.z<<16); s[5]+=__uint_as_float(u.z&0xffff0000u);
      s[6]+=__uint_as_float(u.w<<16); s[7]+=__uint_as_float(u.w&0xffff0000u);
    }
  }
  float* hp = h + n*80 + f0;
  *(float4*)hp       = make_float4(s[0],s[1],s[2],s[3]);
  *(float4*)(hp + 4) = make_float4(s[4],s[5],s[6],s[7]);
}

// ---- atomic-free CSR build: hist -> cscan -> bscan -> place -> csr ----

__global__ __launch_bounds__(256) void k_hist(const int* __restrict__ ei,
                                              int* __restrict__ chunkcnt){
  __shared__ int hist[NBUCK];
  int c = blockIdx.x, t = threadIdx.x;
  for (int i = t; i < NBUCK; i += 256) hist[i] = 0;
  __syncthreads();
  #pragma unroll
  for (int j = 0; j < 16; j++){
    int e = (c << CSH) + j*256 + t;
    if (e < NE) atomicAdd(&hist[ei[NE + e] >> BSH], 1);
  }
  __syncthreads();
  for (int i = t; i < NBUCK; i += 256) chunkcnt[c*NBUCK + i] = hist[i];
}

__global__ __launch_bounds__(256) void k_cscan(int* __restrict__ chunkcnt,
                                               int* __restrict__ btotal){
  __shared__ int buf[256];
  int b = blockIdx.x, t = threadIdx.x;
  int v[4]; int s = 0;
  #pragma unroll
  for (int j = 0; j < 4; j++){
    int c = t*4 + j;
    v[j] = (c < NCH) ? chunkcnt[c*NBUCK + b] : 0;
    s += v[j];
  }
  buf[t] = s;
  __syncthreads();
  for (int off = 1; off < 256; off <<= 1){
    int xv = (t >= off) ? buf[t - off] : 0;
    __syncthreads();
    buf[t] += xv;
    __syncthreads();
  }
  int excl = buf[t] - s;
  #pragma unroll
  for (int j = 0; j < 4; j++){
    int c = t*4 + j;
    if (c < NCH){ chunkcnt[c*NBUCK + b] = excl; excl += v[j]; }
  }
  if (t == 255) btotal[b] = buf[255];
}

__global__ __launch_bounds__(256) void k_bscan(const int* __restrict__ btotal,
                                               int* __restrict__ bbase){
  __shared__ int buf[256];
  int t = threadIdx.x;
  int v[4]; int s = 0;
  #pragma unroll
  for (int j = 0; j < 4; j++){
    int c = t*4 + j;
    v[j] = (c < NBUCK) ? btotal[c] : 0;
    s += v[j];
  }
  buf[t] = s;
  __syncthreads();
  for (int off = 1; off < 256; off <<= 1){
    int xv = (t >= off) ? buf[t - off] : 0;
    __syncthreads();
    buf[t] += xv;
    __syncthreads();
  }
  int excl = buf[t] - s;
  #pragma unroll
  for (int j = 0; j < 4; j++){
    int c = t*4 + j;
    if (c < NBUCK){ bbase[c] = excl; excl += v[j]; }
  }
  if (t == 255) bbase[NBUCK] = buf[255];
}

__global__ __launch_bounds__(256) void k_place(const int* __restrict__ ei,
                        const int* __restrict__ chunkcnt, const int* __restrict__ bbase,
                        int* __restrict__ staging){
  __shared__ int basep[NBUCK];
  __shared__ int cur[NBUCK];
  int c = blockIdx.x, t = threadIdx.x;
  for (int i = t; i < NBUCK; i += 256){
    basep[i] = chunkcnt[c*NBUCK + i] + bbase[i];
    cur[i] = 0;
  }
  __syncthreads();
  #pragma unroll
  for (int j = 0; j < 16; j++){
    int e = (c << CSH) + j*256 + t;
    if (e < NE){
      int d = ei[NE + e], s = ei[e];
      int b = d >> BSH;
      int r = atomicAdd(&cur[b], 1);
      staging[basep[b] + r] = (s << BSH) | (d & 63);
    }
  }
}

__global__ __launch_bounds__(256) void k_csr(const int* __restrict__ staging,
                        const int* __restrict__ bbase, const void* __restrict__ avgp,
                        const int* __restrict__ flag, int* __restrict__ rowptr,
                        float* __restrict__ scf, float* __restrict__ invf,
                        int* __restrict__ colidx){
  __shared__ int lcnt[64], lrp[64], lcur[64];
  __shared__ int colbuf[BCAP];
  int b = blockIdx.x, t = threadIdx.x;
  int base = bbase[b];
  int cnt  = bbase[b+1] - base;
  if (t < 64){ lcnt[t] = 0; lcur[t] = 0; }
  __syncthreads();
  for (int i = t; i < cnt; i += 256)
    atomicAdd(&lcnt[staging[base + i] & 63], 1);
  __syncthreads();
  if (t < 64) lrp[t] = lcnt[t];
  __syncthreads();
  for (int off = 1; off < 64; off <<= 1){
    int xv = (t < 64 && t >= off) ? lrp[t - off] : 0;
    __syncthreads();
    if (t < 64) lrp[t] += xv;
    __syncthreads();
  }
  int n0 = b << BSH;
  if (t < 64){
    int ex = lrp[t] - lcnt[t];
    lrp[t] = ex;
    int n = n0 + t;
    if (n < NN){
      rowptr[n] = base + ex;
      float degc = (float)(lcnt[t] > 0 ? lcnt[t] : 1);
      float logd = logf(degc + 1.f);
      float avg = rdw(avgp, 0, flag[0]);
      scf[n] = logd / avg;
      invf[n] = avg / logd;
    }
  }
  if (b == 0 && t == 0) rowptr[NN] = NE;
  __syncthreads();
  if (cnt <= BCAP){
    for (int i = t; i < cnt; i += 256){
      int v = staging[base + i];
      int l = v & 63;
      int pos = lrp[l] + atomicAdd(&lcur[l], 1);
      colbuf[pos] = v >> BSH;
    }
    __syncthreads();
    for (int i = t; i < cnt; i += 256)
      colidx[base + i] = colbuf[i];
  } else {
    for (int i = t; i < cnt; i += 256){
      int v = staging[base + i];
      int l = v & 63;
      int pos = lrp[l] + atomicAdd(&lcur[l], 1);
      colidx[base + pos] = v >> BSH;
    }
  }
}

// ------------------------------------------------------------------ MFMA GEMM (r4 structure; Wf only)
template<int AF32, int OUTMODE, int K_, int AST>
__global__ __launch_bounds__(256) void k_mgemm(
    const void* __restrict__ A1p, int s1, int KA,
    const bf16* __restrict__ A2, int s2, int KB,
    const bf16* __restrict__ Btp, int Bts, int Ncols,
    const float* __restrict__ bias,
    void* __restrict__ Cbase, void* __restrict__ Cp2, int Cstride, int M,
    int lA1b, int lBtb, int lCb)
{
  const void* A1 = (const char*)A1p + (size_t)blockIdx.z*lA1b;
  const bf16* Bt = (const bf16*)((const char*)Btp + (size_t)blockIdx.z*lBtb);
  void* Cp = (char*)Cbase + (size_t)blockIdx.z*lCb;

  constexpr int NKT = K_ / 32;
  __shared__ short As[64*AST];
  __shared__ short Bs[256*44];

  const int tid = threadIdx.x;
  const int row0 = blockIdx.x * 64;
  const int wave = tid >> 6, lane = tid & 63;
  const int wc = wave * 64;
  const int m16 = lane & 15, q = lane >> 4;

  const int ra = tid >> 2, ka = (tid & 3) * 8;
  const int cb = tid >> 2, kb = (tid & 3) * 8;

  f32x4 acc[4][4] = {};
  uint4 pb[4];

#define LOADB(k0_) { int kgb = (k0_) + kb;                                     \
    _Pragma("unroll")                                                          \
    for (int j = 0; j < 4; j++){                                               \
      int col = cb + j*64;                                                     \
      pb[j].x = pb[j].y = pb[j].z = pb[j].w = 0u;                              \
      if (col < Ncols) pb[j] = *(const uint4*)(Bt + col*Bts + kgb);            \
    } }

  LOADB(0);

  {
    const int grow = row0 + ra;
    uint4 tA[NKT];
    #pragma unroll
    for (int c = 0; c < NKT; c++){
      int kg = c*32 + ka;
      uint4 pa; pa.x = pa.y = pa.z = pa.w = 0u;
      if (grow < M){
        if (kg < KA){
          if (AF32){
            const float* ap = (const float*)A1 + grow*s1 + kg;
            float4 f0 = *(const float4*)ap;
            float4 f1 = *(const float4*)(ap + 4);
            pa.x = pk(f0.x, f0.y); pa.y = pk(f0.z, f0.w);
            pa.z = pk(f1.x, f1.y); pa.w = pk(f1.z, f1.w);
          } else {
            pa = *(const uint4*)((const bf16*)A1 + grow*s1 + kg);
          }
        } else if (kg - KA < KB){
          pa = *(const uint4*)(A2 + grow*s2 + (kg - KA));
        }
      }
      tA[c] = pa;
    }
    #pragma unroll
    for (int c = 0; c < NKT; c++)
      ldsst16(&As[ra*AST + c*32 + ka], tA[c]);
  }
  __syncthreads();

  #pragma unroll
  for (int ks = 0; ks < NKT; ks++){
    #pragma unroll
    for (int j = 0; j < 4; j++)
      ldsst16(&Bs[(cb + j*64)*44 + kb], pb[j]);
    __syncthreads();

    if (ks + 1 < NKT) LOADB((ks + 1)*32);

    bf16x8 af[4], bfv[4];
    #pragma unroll
    for (int rt = 0; rt < 4; rt++)
      af[rt] = ldsld8(&As[(rt*16 + m16)*AST + ks*32 + q*8]);
    #pragma unroll
    for (int ct = 0; ct < 4; ct++)
      bfv[ct] = ldsld8(&Bs[(wc + ct*16 + m16)*44 + q*8]);
    #pragma unroll
    for (int rt = 0; rt < 4; rt++)
      #pragma unroll
      for (int ct = 0; ct < 4; ct++)
        acc[rt][ct] = __builtin_amdgcn_mfma_f32_16x16x32_bf16(af[rt], bfv[ct], acc[rt][ct], 0, 0, 0);
    __syncthreads();
  }
#undef LOADB

  #pragma unroll
  for (int rt = 0; rt < 4; rt++){
    #pragma unroll
    for (int rr = 0; rr < 4; rr++){
      int row = row0 + rt*16 + q*4 + rr;
      if (row >= M) continue;
      #pragma unroll
      for (int ct = 0; ct < 4; ct++){
        int col = wc + ct*16 + m16;
        if (col >= Ncols) continue;
        float v = acc[rt][ct][rr] + (bias ? bias[col] : 0.f);
        if (OUTMODE == 1) ((float*)Cp)[row*Cstride + col] = v;
        else {
          if (col < 80) ((bf16*)Cp )[row*80 + col]      = f2b(v);
          else          ((bf16*)Cp2)[row*80 + col - 80] = f2b(v);
        }
      }
    }
  }
}

// ------------------------------------------------------------------ layer-0 GEMM1 (direct tiled-B, barrier-free)
__global__ __launch_bounds__(256) void k_g1(
    const float* __restrict__ h, const bf16* __restrict__ Bt1t,
    const float* __restrict__ bias1v,
    bf16* __restrict__ Ua, bf16* __restrict__ Ub)
{
  __shared__ short hA[32*100];   // 6,400 B
  const int tid = threadIdx.x;
  const int row0 = blockIdx.x * 32;
  const int wave = tid >> 6, lane = tid & 63;
  const int wc = wave * 64;
  const int m16 = lane & 15, q = lane >> 4;
  const int ra = tid >> 3, ka0 = (tid & 7) * 8;

  // stage h rows (f32->bf16); zero pad k in [80,96)
  {
    int grow = row0 + ra;
    #pragma unroll
    for (int c = 0; c < 2; c++){
      int kg = ka0 + c*64;
      if (kg < 96){
        uint4 pa; pa.x = pa.y = pa.z = pa.w = 0u;
        if (kg < 80 && grow < NN){
          const float* ap = h + grow*80 + kg;
          float4 f0 = *(const float4*)ap, f1 = *(const float4*)(ap + 4);
          pa.x = pk(f0.x, f0.y); pa.y = pk(f0.z, f0.w);
          pa.z = pk(f1.x, f1.y); pa.w = pk(f1.z, f1.w);
        }
        ldsst16(&hA[ra*100 + kg], pa);
      }
    }
  }
  __syncthreads();

  const bf16* bp1[4];
  #pragma unroll
  for (int ct = 0; ct < 4; ct++){
    int col = wc + ct*16 + m16;
    if (col >= 160) col = 0;
    bp1[ct] = Bt1t + col*32 + q*8;
  }
  f32x4 acc[2][4] = {};
  #pragma unroll
  for (int ks = 0; ks < 3; ks++){
    bf16x8 bfv[4], af[2];
    #pragma unroll
    for (int ct = 0; ct < 4; ct++)
      bfv[ct] = *(const bf16x8*)(bp1[ct] + ks*5120);
    #pragma unroll
    for (int rt = 0; rt < 2; rt++)
      af[rt] = ldsld8(&hA[(rt*16 + m16)*100 + ks*32 + q*8]);
    #pragma unroll
    for (int rt = 0; rt < 2; rt++)
      #pragma unroll
      for (int ct = 0; ct < 4; ct++)
        acc[rt][ct] = __builtin_amdgcn_mfma_f32_16x16x32_bf16(af[rt], bfv[ct], acc[rt][ct], 0, 0, 0);
  }
  #pragma unroll
  for (int rt = 0; rt < 2; rt++){
    #pragma unroll
    for (int rr = 0; rr < 4; rr++){
      int row = row0 + rt*16 + q*4 + rr;
      if (row >= NN) continue;
      #pragma unroll
      for (int ct = 0; ct < 4; ct++){
        int col = wc + ct*16 + m16;
        if (col >= 160) continue;
        float v = acc[rt][ct][rr] + bias1v[col];
        if (col < 80) Ua[row*80 + col]      = f2b(v);
        else          Ub[row*80 + col - 80] = f2b(v);
      }
    }
  }
}

// ------------------------------------------------------------------ GEMM2 + fused next-layer GEMM1
// 32-row tile, direct tiled-B, barrier-free K-loop (r12 form, 53.2us measured
// best; round-13 evidence: explicit depth-2 prefetch with conditional buffer
// select SERIALIZED the loop, 53->66us -> reverted).
// LDS = As only (26,880 B) -> 5 blocks/CU.
__global__ __launch_bounds__(256) void k_g2(
    const float* __restrict__ h, const bf16* __restrict__ agg,
    const bf16* __restrict__ Bt, const float* __restrict__ bias2v,
    const float* __restrict__ scf, const float* __restrict__ invf,
    float* __restrict__ hp,
    const bf16* __restrict__ Bt1n, const float* __restrict__ bias1n,
    bf16* __restrict__ Ua, bf16* __restrict__ Ub)
{
  constexpr int AST = 420, NKT = 13;
  __shared__ short As[32*AST];   // 26,880 B
  bf16* eL = (bf16*)As;                 // epilogue staging 32x248 (15,872 B)
  bf16* hA = (bf16*)(As + 8192);        // h_new panel 32x100 (bytes 16,384..22,784)

  const int tid = threadIdx.x;
  const int row0 = blockIdx.x * 32;
  const int wave = tid >> 6, lane = tid & 63;
  const int wc = wave * 64;
  const int m16 = lane & 15, q = lane >> 4;
  const int ra = tid >> 3;           // 32 rows, 8 threads/row
  const int ka0 = (tid & 7) * 8;     // chunk start; stride 64 shorts

  // ---- stage A panel: k<80 from h (f32->bf16), 80<=k<400 from agg, else 0
  {
    const int grow = row0 + ra;
    uint4 tA[7];
    #pragma unroll
    for (int c = 0; c < 7; c++){
      int kg = ka0 + c*64;
      uint4 pa; pa.x = pa.y = pa.z = pa.w = 0u;
      if (kg < 416 && grow < NN){
        if (kg < 80){
          const float* ap = h + grow*80 + kg;
          float4 f0 = *(const float4*)ap;
          float4 f1 = *(const float4*)(ap + 4);
          pa.x = pk(f0.x, f0.y); pa.y = pk(f0.z, f0.w);
          pa.z = pk(f1.x, f1.y); pa.w = pk(f1.z, f1.w);
        } else if (kg < 400){
          pa = *(const uint4*)(agg + grow*320 + (kg - 80));
        }
      }
      tA[c] = pa;
    }
    #pragma unroll
    for (int c = 0; c < 7; c++){
      int kg = ka0 + c*64;
      if (kg < 416) ldsst16(&As[ra*AST + kg], tA[c]);
    }
  }

  // ---- per-lane tiled-B base pointers (OOB cols clamped; their acc unused)
  const bf16* bp[4];
  #pragma unroll
  for (int ct = 0; ct < 4; ct++){
    int col = wc + ct*16 + m16;
    if (col >= 240) col = 0;
    bp[ct] = Bt + col*32 + q*8;
  }
  __syncthreads();   // A panel ready

  f32x4 acc[2][4] = {};

  // ---- barrier-free K loop: direct-global B frags (contiguous 1KB/wave/frag)
  #pragma unroll
  for (int ks = 0; ks < NKT; ks++){
    bf16x8 bfv[4], af[2];
    #pragma unroll
    for (int ct = 0; ct < 4; ct++)
      bfv[ct] = *(const bf16x8*)(bp[ct] + ks*7680);
    #pragma unroll
    for (int rt = 0; rt < 2; rt++)
      af[rt] = ldsld8(&As[(rt*16 + m16)*AST + ks*32 + q*8]);
    #pragma unroll
    for (int rt = 0; rt < 2; rt++)
      #pragma unroll
      for (int ct = 0; ct < 4; ct++)
        acc[rt][ct] = __builtin_amdgcn_mfma_f32_16x16x32_bf16(af[rt], bfv[ct], acc[rt][ct], 0, 0, 0);
  }
  __syncthreads();   // all waves done reading As before eL overwrite

  // ---- epilogue: stage P|Q|R in eL
  #pragma unroll
  for (int rt = 0; rt < 2; rt++){
    #pragma unroll
    for (int ct = 0; ct < 4; ct++){
      int col = wc + ct*16 + m16;
      if (col >= 240) continue;
      #pragma unroll
      for (int rr = 0; rr < 4; rr++){
        int r = rt*16 + q*4 + rr;
        eL[r*248 + col] = f2b(acc[rt][ct][rr]);
      }
    }
  }
  __syncthreads();

  // ---- combine -> h_new; write global f32 + LDS bf16 panel
  #pragma unroll
  for (int i = 0; i < 10; i++){
    int idx = tid + i*256;
    int r = idx / 80, c = idx - r*80;
    int row = row0 + r;
    if (row < NN){
      float P = b2f(eL[r*248 + c]);
      float Q = b2f(eL[r*248 + 80 + c]);
      float R = b2f(eL[r*248 + 160 + c]);
      float o = P + scf[row]*Q + invf[row]*R + bias2v[c];
      float hn = hp[row*80 + c] + fmaxf(o, 0.f);
      hp[row*80 + c] = hn;
      if (Bt1n) hA[r*100 + c] = f2b(hn);
    } else if (Bt1n && idx < 32*80){
      hA[r*100 + c] = f2b(0.f);   // tail rows: defined values for mini-GEMM
    }
  }
  if (Bt1n && tid < 128){
    // zero pad k in [80,96)
    int r = tid >> 2, off = 80 + (tid & 3)*4;
    *(uint2*)&hA[r*100 + off] = make_uint2(0u, 0u);
  }
  __syncthreads();

  // ---- mini-GEMM: U = h_new @ Bt1[next] (tiled-B, barrier-free)
  if (Bt1n){
    const bf16* bp1[4];
    #pragma unroll
    for (int ct = 0; ct < 4; ct++){
      int col = wc + ct*16 + m16;
      if (col >= 160) col = 0;
      bp1[ct] = Bt1n + col*32 + q*8;
    }
    f32x4 acc2[2][4] = {};
    #pragma unroll
    for (int ks = 0; ks < 3; ks++){
      bf16x8 bfv[4], af[2];
      #pragma unroll
      for (int ct = 0; ct < 4; ct++)
        bfv[ct] = *(const bf16x8*)(bp1[ct] + ks*5120);
      #pragma unroll
      for (int rt = 0; rt < 2; rt++)
        af[rt] = ldsld8((const short*)hA + (rt*16 + m16)*100 + ks*32 + q*8);
      #pragma unroll
      for (int rt = 0; rt < 2; rt++)
        #pragma unroll
        for (int ct = 0; ct < 4; ct++)
          acc2[rt][ct] = __builtin_amdgcn_mfma_f32_16x16x32_bf16(af[rt], bfv[ct], acc2[rt][ct], 0, 0, 0);
    }
    #pragma unroll
    for (int rt = 0; rt < 2; rt++){
      #pragma unroll
      for (int rr = 0; rr < 4; rr++){
        int row = row0 + rt*16 + q*4 + rr;
        if (row >= NN) continue;
        #pragma unroll
        for (int ct = 0; ct < 4; ct++){
          int col = wc + ct*16 + m16;
          if (col >= 160) continue;
          float v = acc2[rt][ct][rr] + bias1n[col];
          if (col < 80) Ua[row*80 + col]      = f2b(v);
          else          Ub[row*80 + col - 80] = f2b(v);
        }
      }
    }
  }
}

// ------------------------------------------------------------------ aggregation
// 3 nodes/wave: lane/20 = node slot, (lane%20)*4 = feature offset.
// Batch 16 (mean degree): 16 gathers in flight per lane (r13-measured win).
__global__ __launch_bounds__(256) void k_agg(const bf16* __restrict__ Ua,
                      const bf16* __restrict__ Ub,
                      const int* __restrict__ rowptr,
                      const int* __restrict__ colidx, bf16* __restrict__ agg)
{
  int lane = threadIdx.x & 63;
  int slot = lane / 20;
  int n = blockIdx.x*12 + (threadIdx.x >> 6)*3 + slot;
  if (slot >= 3 || n >= NN) return;
  int fo = (lane - slot*20) * 4;
  int rs = rowptr[n], re = rowptr[n+1];
  int deg = re - rs;

  float a[4];
  {
    uint2 ua = *(const uint2*)(Ua + n*80 + fo);
    a[0] = __uint_as_float(ua.x << 16);
    a[1] = __uint_as_float(ua.x & 0xffff0000u);
    a[2] = __uint_as_float(ua.y << 16);
    a[3] = __uint_as_float(ua.y & 0xffff0000u);
  }
  float sb[4] = {0.f,0.f,0.f,0.f}, sq[4] = {0.f,0.f,0.f,0.f};
  float mn[4] = {1e30f,1e30f,1e30f,1e30f}, mx[4] = {-1e30f,-1e30f,-1e30f,-1e30f};

#define ACC2(w, o) { \
    float b0 = __uint_as_float((w) << 16); \
    float b1 = __uint_as_float((w) & 0xffff0000u); \
    sb[o] += b0; sq[o] += b0*b0; mn[o] = fminf(mn[o],b0); mx[o] = fmaxf(mx[o],b0); \
    sb[o+1] += b1; sq[o+1] += b1*b1; mn[o+1] = fminf(mn[o+1],b1); mx[o+1] = fmaxf(mx[o+1],b1); }

  for (int e = rs; e < re; e += 16){
    int cnt = re - e; if (cnt > 16) cnt = 16;
    int s[16];
    #pragma unroll
    for (int j = 0; j < 16; j++) s[j] = (j < cnt) ? colidx[e + j] : s[0];
    uint2 u[16];
    #pragma unroll
    for (int j = 0; j < 16; j++) u[j] = *(const uint2*)(Ub + s[j]*80 + fo);
    #pragma unroll
    for (int j = 0; j < 16; j++){
      if (j < cnt){ ACC2(u[j].x, 0); ACC2(u[j].y, 2); }
    }
  }
#undef ACC2

  float degc = (float)(deg > 0 ? deg : 1);
  float inv = 1.f/degc;
  float dm = (float)deg;
  float mean0, mean1, v0, v1, sd0, sd1, lo0, lo1, hi0, hi1;

  mean0 = (dm*a[0] + sb[0])*inv; mean1 = (dm*a[1] + sb[1])*inv;
  v0 = (dm*a[0]*a[0] + 2.f*a[0]*sb[0] + sq[0])*inv - mean0*mean0;
  v1 = (dm*a[1]*a[1] + 2.f*a[1]*sb[1] + sq[1])*inv - mean1*mean1;
  sd0 = sqrtf(fmaxf(v0,0.f)+1e-5f); sd1 = sqrtf(fmaxf(v1,0.f)+1e-5f);
  lo0 = deg>0 ? a[0]+mn[0] : 0.f; lo1 = deg>0 ? a[1]+mn[1] : 0.f;
  hi0 = deg>0 ? a[0]+mx[0] : 0.f; hi1 = deg>0 ? a[1]+mx[1] : 0.f;
  unsigned o0 = pk(mean0, mean1);
  unsigned l0 = pk(lo0, lo1), h0 = pk(hi0, hi1), t0 = pk(sd0, sd1);

  mean0 = (dm*a[2] + sb[2])*inv; mean1 = (dm*a[3] + sb[3])*inv;
  v0 = (dm*a[2]*a[2] + 2.f*a[2]*sb[2] + sq[2])*inv - mean0*mean0;
  v1 = (dm*a[3]*a[3] + 2.f*a[3]*sb[3] + sq[3])*inv - mean1*mean1;
  sd0 = sqrtf(fmaxf(v0,0.f)+1e-5f); sd1 = sqrtf(fmaxf(v1,0.f)+1e-5f);
  lo0 = deg>0 ? a[2]+mn[2] : 0.f; lo1 = deg>0 ? a[3]+mn[3] : 0.f;
  hi0 = deg>0 ? a[2]+mx[2] : 0.f; hi1 = deg>0 ? a[3]+mx[3] : 0.f;
  unsigned o1 = pk(mean0, mean1);
  unsigned l1 = pk(lo0, lo1), h1 = pk(hi0, hi1), t1 = pk(sd0, sd1);

  bf16* ag = agg + n*320 + fo;
  *(uint2*)(ag)       = make_uint2(o0, o1);
  *(uint2*)(ag + 80)  = make_uint2(l0, l1);
  *(uint2*)(ag + 160) = make_uint2(h0, h1);
  *(uint2*)(ag + 240) = make_uint2(t0, t1);
}

// ------------------------------------------------------------------ fused mean-pool + head
__global__ __launch_bounds__(128) void k_poolmlp(const float* __restrict__ h,
                        const int* __restrict__ batch,
                        const void* __restrict__ mlpW, const void* __restrict__ mlpb,
                        const int* __restrict__ flag, void* __restrict__ outp){
  __shared__ float sred[128];
  __shared__ int sb[2];
  int g = blockIdx.x;
  int t = threadIdx.x;
  if (t < 2){
    int target = g + t;
    int lo = 0, hi = NN;
    while (lo < hi){ int mid = (lo + hi) >> 1; if (batch[mid] < target) lo = mid + 1; else hi = mid; }
    sb[t] = lo;
  }
  __syncthreads();
  int lo = sb[0], hi = sb[1];
  float s = 0.f;
  if (t < 80)
    for (int n = lo; n < hi; n++) s += h[n*80 + t];
  int fl = flag[0];
  float wv = (t < 80) ? rdw(mlpW, t, fl) : 0.f;
  sred[t] = s * wv;
  __syncthreads();
  for (int off = 64; off > 0; off >>= 1){
    if (t < off) sred[t] += sred[t + off];
    __syncthreads();
  }
  if (t == 0){
    float cnt = (float)(hi - lo); if (cnt < 1.f) cnt = 1.f;
    float r = sred[0]/cnt + rdw(mlpb, 0, fl);
    if (fl) ((float*)outp)[g] = r;
    else    ((bf16*)outp)[g] = f2b(r);
  }
}

// ------------------------------------------------------------------ launch
extern "C" void kernel_launch(void* const* d_in, const int* in_sizes, int n_in,
                              void* d_out, int out_size, void* d_ws, size_t ws_size,
                              hipStream_t stream)
{
  const int*  x     = (const int*) d_in[0];
  const int*  ei    = (const int*) d_in[1];
  const int*  batch = (const int*) d_in[2];
  const void* avgp  = d_in[3];
  const void* aemb  = d_in[4];
  const void* preW  = d_in[5];
  const void* preb  = d_in[6];
  const void* postW = d_in[7];
  const void* postb = d_in[8];
  const void* linW  = d_in[9];
  const void* linb  = d_in[10];
  const void* bng   = d_in[11];
  const void* bnb   = d_in[12];
  const void* bnm   = d_in[13];
  const void* bnv   = d_in[14];
  const void* mlpW  = d_in[15];
  const void* mlpb  = d_in[16];

  char* w = (char*)d_ws;
  int*   flag   = (int*)  (w + 400000);       //       256  (zeroed)
  int*   rowptr = (int*)  (w + 401280);       //   200,064
  int*   colidx = (int*)  (w + 601344);       // 3,200,000
  float* scf    = (float*)(w + 3801344);      //   200,000
  float* invf   = (float*)(w + 4001344);      //   200,000
  float* bias1  = (float*)(w + 4201344);      //     2,560
  float* bias2  = (float*)(w + 4203904);      //     1,280
  bf16*  Btl    = (bf16*) (w + 4205184);      //    61,440
  bf16*  Bt1    = (bf16*) (w + 4266624);      //   122,880  (tiled layout)
  bf16*  Bt2    = (bf16*) (w + 4389504);      //   798,720  (tiled layout)
  float* h      = (float*)(w + 5188224);      // 16,000,000  f32 [N,80]
  bf16*  Ua     = (bf16*) (w + 21188224);     //  8,000,000  bf16 [N,80]
  bf16*  Ub     = (bf16*) (w + 29188224);     //  8,000,000  bf16 [N,80]
  bf16*  agg    = (bf16*) (w + 45188224);     // 32,000,000  bf16 [N,320]
  // pre-loop overlays inside the agg region:
  bf16*  pwb    = (bf16*) (w + 45188224);     //   665,600
  float* Wf     = (float*)(w + 45853824);     // 1,331,200
  int* staging  = (int*)  (w + 47185024);     // 3,200,000
  int* chunkcnt = (int*)  (w + 50385024);     //   613,088  [NCH][NBUCK]
  int* btotal   = (int*)  (w + 52831120);     //     3,128
  int* bbase    = (int*)  (w + 52834248);     //     3,136  (NBUCK+1)
  // total 77,188,224 B

  k_zero <<<1, 256, 0, stream>>>(flag, 64);
  k_probe<<<16, 256, 0, stream>>>(aemb, flag);

  // atomic-free CSR build
  k_hist <<<NCH, 256, 0, stream>>>(ei, chunkcnt);
  k_cscan<<<NBUCK, 256, 0, stream>>>(chunkcnt, btotal);
  k_bscan<<<1, 256, 0, stream>>>(btotal, bbase);
  k_place<<<NCH, 256, 0, stream>>>(ei, chunkcnt, bbase, staging);

  k_prep_all<<<1662, 256, 0, stream>>>(preW, preb, postW, postb, linW, linb,
                                       bng, bnb, bnm, bnv, flag,
                                       pwb, Btl, Bt1, bias1, bias2);

  // Wf[i] = postW[i](bf16) @ Btl[i]^T   (f32 out)
  k_mgemm<0,1,96,100><<<dim3(17,1,4), 256, 0, stream>>>(
      pwb, 80, 80, nullptr, 0, 0,
      Btl, 96, 80, nullptr, Wf, nullptr, 80, 1040,
      166400, 15360, 332800);
  k_prep_Bt2<<<(4*240*416 + 255)/256, 256, 0, stream>>>(Wf, Bt2);

  k_atom <<<(NN*10 + 255)/256, 256, 0, stream>>>(x, aemb, flag, h);

  // fused rowptr/scf/invf + counting-sorted colidx
  k_csr<<<NBUCK, 256, 0, stream>>>(staging, bbase, avgp, flag, rowptr, scf, invf, colidx);

  const int gx2 = (NN + 31)/32;   // 1563
  // layer-0 GEMM1 (subsequent layers' GEMM1 are fused into k_g2's tail)
  k_g1<<<dim3(gx2,1,1), 256, 0, stream>>>(h, Bt1, bias1, Ua, Ub);
  for (int i = 0; i < 4; i++){
    k_agg<<<(NN + 11)/12, 256, 0, stream>>>(Ua, Ub, rowptr, colidx, agg);
    const bf16* nBt1   = (i < 3) ? (Bt1 + (i+1)*15360) : nullptr;
    const float* nb1   = (i < 3) ? (bias1 + (i+1)*160) : bias1;
    k_g2<<<dim3(gx2,1,1), 256, 0, stream>>>(
        h, agg, Bt2 + i*99840, bias2 + i*80, scf, invf, h,
        nBt1, nb1, Ua, Ub);
  }

  k_poolmlp<<<NGR, 128, 0, stream>>>(h, batch, mlpW, mlpb, flag, d_out);
}

// Round 15
// 514.770 us; speedup vs baseline: 1.0171x; 1.0171x over previous
//
#include <hip/hip_runtime.h>
#include <hip/hip_bf16.h>

#define NN 50000
#define NE 800000
#define FD 80
#define NGR 1024
#define NF 9

// bucketed CSR sort (atomic-free counting sort)
#define BSH 6
#define NBUCK ((NN + 63) >> 6)     // 782 node-buckets of 64
#define CSH 12
#define NCH ((NE + 4095) >> 12)    // 196 edge-chunks of 4096
#define BCAP 2048

using bf16 = __hip_bfloat16;
typedef __attribute__((ext_vector_type(8))) short bf16x8;
typedef __attribute__((ext_vector_type(4))) float f32x4;

static __device__ __forceinline__ float b2f(bf16 v){ return __bfloat162float(v); }
static __device__ __forceinline__ bf16 f2b(float v){ return __float2bfloat16(v); }
static __device__ __forceinline__ float rdw(const void* p, int i, int fl){
  return fl ? ((const float*)p)[i] : b2f(((const bf16*)p)[i]);
}
static __device__ __forceinline__ unsigned pk(float a, float b){
  bf16 x = f2b(a), y = f2b(b);
  return (unsigned)*(unsigned short*)&x | ((unsigned)*(unsigned short*)&y << 16);
}
// 8B-granule LDS access (strides are 8B- but not 16B-aligned)
static __device__ __forceinline__ bf16x8 ldsld8(const short* p){
  union { bf16x8 v; uint2 u[2]; } r;
  r.u[0] = *(const uint2*)(p);
  r.u[1] = *(const uint2*)(p + 4);
  return r.v;
}
static __device__ __forceinline__ void ldsst16(short* p, uint4 v){
  *(uint2*)(p)     = make_uint2(v.x, v.y);
  *(uint2*)(p + 4) = make_uint2(v.z, v.w);
}

// ------------------------------------------------------------------ utility
__global__ void k_zero(int* __restrict__ p, int n){
  int t = blockIdx.x*256 + threadIdx.x;
  if (t < n) p[t] = 0;
}

__global__ void k_probe(const void* __restrict__ emb, int* __restrict__ flag){
  int t = blockIdx.x*256 + threadIdx.x;
  float v = b2f(((const bf16*)emb)[t]);
  if (!(fabsf(v) < 1e4f)) atomicOr(flag, 1);
}

// ------------------------------------------------------------------ fused weight prep
// Bt1/Bt2 in K-step-major FRAGMENT-TILED layout (r12 win): one wave's MFMA
// B-frag load is a contiguous 1KB segment (direct-global, no LDS staging).
__global__ __launch_bounds__(256) void k_prep_all(
    const void* __restrict__ preW, const void* __restrict__ preb,
    const void* __restrict__ postW, const void* __restrict__ postb,
    const void* __restrict__ linW, const void* __restrict__ linb,
    const void* __restrict__ bng, const void* __restrict__ bnb,
    const void* __restrict__ bnm, const void* __restrict__ bnv,
    const int* __restrict__ flag,
    bf16* __restrict__ pwb, bf16* __restrict__ Btl, bf16* __restrict__ Bt1,
    float* __restrict__ bias1, float* __restrict__ bias2)
{
  int fl = flag[0];
  int b = blockIdx.x;
  if (b < 1300){
    int t = b*256 + threadIdx.x;
    pwb[t] = f2b(rdw(postW, t, fl));
  } else if (b < 1420){
    int t = (b - 1300)*256 + threadIdx.x;
    int j = t % 96, c = (t/96) % 80, i = t/(96*80);
    float v = 0.f;
    if (j < 80){
      float gs = rdw(bng, i*80 + c, fl) * rsqrtf(rdw(bnv, i*80 + c, fl) + 1e-5f);
      v = rdw(linW, i*6400 + j*80 + c, fl) * gs;
    }
    Btl[t] = f2b(v);
  } else if (b < 1660){
    int t = (b - 1420)*256 + threadIdx.x;
    int k = t % 96, c = (t/96) % 160, i = t/(96*160);
    float v = 0.f;
    if (k < 80)
      v = (c < 80) ? rdw(preW, (i*160 + k)*80 + c, fl)
                   : rdw(preW, (i*160 + 80 + k)*80 + (c - 80), fl);
    int of = ((k >> 5)*160 + c)*32 + (k & 31);
    Bt1[i*15360 + of] = f2b(v);
    if (k == 0) bias1[i*160 + c] = (c < 80) ? rdw(preb, i*80 + c, fl) : 0.f;
  } else {
    int t = (b - 1660)*256 + threadIdx.x;
    if (t >= 4*80) return;
    int i = t / 80, f = t - i*80;
    float s = 0.f;
    for (int j = 0; j < 80; j++)
      s += rdw(postb, i*80 + j, fl) * rdw(linW, (i*80 + j)*80 + f, fl);
    s += rdw(linb, t, fl);
    float gs = rdw(bng, t, fl) * rsqrtf(rdw(bnv, t, fl) + 1e-5f);
    bias2[t] = (s - rdw(bnm, t, fl)) * gs + rdw(bnb, t, fl);
  }
}

// Bt2 in fragment-tiled layout: element (c,k) at ks*240*32 + c*32 + (k&31).
__global__ void k_prep_Bt2(const float* __restrict__ Wf, bf16* __restrict__ Bt2){
  int t = blockIdx.x*256 + threadIdx.x;
  if (t >= 4*240*416) return;
  int k = t % 416;
  int c = (t/416) % 240;
  int i = t/(416*240);
  float v = 0.f;
  if (k < 400){
    int blk = c/80, f = c - blk*80;
    if (blk == 0) v = Wf[(i*1040 + k)*80 + f];
    else if (k >= 80){
      int row = (blk == 1 ? 400 : 720) + (k - 80);
      v = Wf[(i*1040 + row)*80 + f];
    }
  }
  int of = (k >> 5)*7680 + c*32 + (k & 31);
  Bt2[i*99840 + of] = f2b(v);
}

// ------------------------------------------------------------------ graph prep
__global__ void k_atom(const int* __restrict__ x, const void* __restrict__ emb,
                       const int* __restrict__ flag, float* __restrict__ h){
  int fl = flag[0];
  int gid = blockIdx.x*256 + threadIdx.x;
  if (gid >= NN*10) return;
  int n = gid / 10, fb = gid - n*10;
  int f0 = fb*8;
  int xr[NF];
  #pragma unroll
  for (int c = 0; c < NF; c++) xr[c] = x[n*NF + c];
  float s[8] = {0.f,0.f,0.f,0.f,0.f,0.f,0.f,0.f};
  if (fl){
    #pragma unroll
    for (int c = 0; c < NF; c++){
      const float* ep = (const float*)emb + (c*119 + xr[c])*80 + f0;
      float4 a = *(const float4*)ep, b = *(const float4*)(ep + 4);
      s[0]+=a.x; s[1]+=a.y; s[2]+=a.z; s[3]+=a.w;
      s[4]+=b.x; s[5]+=b.y; s[6]+=b.z; s[7]+=b.w;
    }
  } else {
    #pragma unroll
    for (int c = 0; c < NF; c++){
      const bf16* ep = (const bf16*)emb + (c*119 + xr[c])*80 + f0;
      uint4 u = *(const uint4*)ep;
      s[0]+=__uint_as_float(u.x<<16); s[1]+=__uint_as_float(u.x&0xffff0000u);
      s[2]+=__uint_as_float(u.y<<16); s[3]+=__uint_as_float(u.y&0xffff0000u);
      s[4]+=__uint_as_float(u.z<<16); s[5]+=__uint_as_float(u.z&0xffff0000u);
      s[6]+=__uint_as_float(u.w<<16); s[7]+=__uint_as_float(u.w&0xffff0000u);
    }
  }
  float* hp = h + n*80 + f0;
  *(float4*)hp       = make_float4(s[0],s[1],s[2],s[3]);
  *(float4*)(hp + 4) = make_float4(s[4],s[5],s[6],s[7]);
}

// ---- atomic-free CSR build: hist -> cscan -> bscan -> place -> csr ----

__global__ __launch_bounds__(256) void k_hist(const int* __restrict__ ei,
                                              int* __restrict__ chunkcnt){
  __shared__ int hist[NBUCK];
  int c = blockIdx.x, t = threadIdx.x;
  for (int i = t; i < NBUCK; i += 256) hist[i] = 0;
  __syncthreads();
  #pragma unroll
  for (int j = 0; j < 16; j++){
    int e = (c << CSH) + j*256 + t;
    if (e < NE) atomicAdd(&hist[ei[NE + e] >> BSH], 1);
  }
  __syncthreads();
  for (int i = t; i < NBUCK; i += 256) chunkcnt[c*NBUCK + i] = hist[i];
}

__global__ __launch_bounds__(256) void k_cscan(int* __restrict__ chunkcnt,
                                               int* __restrict__ btotal){
  __shared__ int buf[256];
  int b = blockIdx.x, t = threadIdx.x;
  int v[4]; int s = 0;
  #pragma unroll
  for (int j = 0; j < 4; j++){
    int c = t*4 + j;
    v[j] = (c < NCH) ? chunkcnt[c*NBUCK + b] : 0;
    s += v[j];
  }
  buf[t] = s;
  __syncthreads();
  for (int off = 1; off < 256; off <<= 1){
    int xv = (t >= off) ? buf[t - off] : 0;
    __syncthreads();
    buf[t] += xv;
    __syncthreads();
  }
  int excl = buf[t] - s;
  #pragma unroll
  for (int j = 0; j < 4; j++){
    int c = t*4 + j;
    if (c < NCH){ chunkcnt[c*NBUCK + b] = excl; excl += v[j]; }
  }
  if (t == 255) btotal[b] = buf[255];
}

__global__ __launch_bounds__(256) void k_bscan(const int* __restrict__ btotal,
                                               int* __restrict__ bbase){
  __shared__ int buf[256];
  int t = threadIdx.x;
  int v[4]; int s = 0;
  #pragma unroll
  for (int j = 0; j < 4; j++){
    int c = t*4 + j;
    v[j] = (c < NBUCK) ? btotal[c] : 0;
    s += v[j];
  }
  buf[t] = s;
  __syncthreads();
  for (int off = 1; off < 256; off <<= 1){
    int xv = (t >= off) ? buf[t - off] : 0;
    __syncthreads();
    buf[t] += xv;
    __syncthreads();
  }
  int excl = buf[t] - s;
  #pragma unroll
  for (int j = 0; j < 4; j++){
    int c = t*4 + j;
    if (c < NBUCK){ bbase[c] = excl; excl += v[j]; }
  }
  if (t == 255) bbase[NBUCK] = buf[255];
}

__global__ __launch_bounds__(256) void k_place(const int* __restrict__ ei,
                        const int* __restrict__ chunkcnt, const int* __restrict__ bbase,
                        int* __restrict__ staging){
  __shared__ int basep[NBUCK];
  __shared__ int cur[NBUCK];
  int c = blockIdx.x, t = threadIdx.x;
  for (int i = t; i < NBUCK; i += 256){
    basep[i] = chunkcnt[c*NBUCK + i] + bbase[i];
    cur[i] = 0;
  }
  __syncthreads();
  #pragma unroll
  for (int j = 0; j < 16; j++){
    int e = (c << CSH) + j*256 + t;
    if (e < NE){
      int d = ei[NE + e], s = ei[e];
      int b = d >> BSH;
      int r = atomicAdd(&cur[b], 1);
      staging[basep[b] + r] = (s << BSH) | (d & 63);
    }
  }
}

__global__ __launch_bounds__(256) void k_csr(const int* __restrict__ staging,
                        const int* __restrict__ bbase, const void* __restrict__ avgp,
                        const int* __restrict__ flag, int* __restrict__ rowptr,
                        float* __restrict__ scf, float* __restrict__ invf,
                        int* __restrict__ colidx){
  __shared__ int lcnt[64], lrp[64], lcur[64];
  __shared__ int colbuf[BCAP];
  int b = blockIdx.x, t = threadIdx.x;
  int base = bbase[b];
  int cnt  = bbase[b+1] - base;
  if (t < 64){ lcnt[t] = 0; lcur[t] = 0; }
  __syncthreads();
  for (int i = t; i < cnt; i += 256)
    atomicAdd(&lcnt[staging[base + i] & 63], 1);
  __syncthreads();
  if (t < 64) lrp[t] = lcnt[t];
  __syncthreads();
  for (int off = 1; off < 64; off <<= 1){
    int xv = (t < 64 && t >= off) ? lrp[t - off] : 0;
    __syncthreads();
    if (t < 64) lrp[t] += xv;
    __syncthreads();
  }
  int n0 = b << BSH;
  if (t < 64){
    int ex = lrp[t] - lcnt[t];
    lrp[t] = ex;
    int n = n0 + t;
    if (n < NN){
      rowptr[n] = base + ex;
      float degc = (float)(lcnt[t] > 0 ? lcnt[t] : 1);
      float logd = logf(degc + 1.f);
      float avg = rdw(avgp, 0, flag[0]);
      scf[n] = logd / avg;
      invf[n] = avg / logd;
    }
  }
  if (b == 0 && t == 0) rowptr[NN] = NE;
  __syncthreads();
  if (cnt <= BCAP){
    for (int i = t; i < cnt; i += 256){
      int v = staging[base + i];
      int l = v & 63;
      int pos = lrp[l] + atomicAdd(&lcur[l], 1);
      colbuf[pos] = v >> BSH;
    }
    __syncthreads();
    for (int i = t; i < cnt; i += 256)
      colidx[base + i] = colbuf[i];
  } else {
    for (int i = t; i < cnt; i += 256){
      int v = staging[base + i];
      int l = v & 63;
      int pos = lrp[l] + atomicAdd(&lcur[l], 1);
      colidx[base + pos] = v >> BSH;
    }
  }
}

// ------------------------------------------------------------------ MFMA GEMM (r4 structure; Wf only)
template<int AF32, int OUTMODE, int K_, int AST>
__global__ __launch_bounds__(256) void k_mgemm(
    const void* __restrict__ A1p, int s1, int KA,
    const bf16* __restrict__ A2, int s2, int KB,
    const bf16* __restrict__ Btp, int Bts, int Ncols,
    const float* __restrict__ bias,
    void* __restrict__ Cbase, void* __restrict__ Cp2, int Cstride, int M,
    int lA1b, int lBtb, int lCb)
{
  const void* A1 = (const char*)A1p + (size_t)blockIdx.z*lA1b;
  const bf16* Bt = (const bf16*)((const char*)Btp + (size_t)blockIdx.z*lBtb);
  void* Cp = (char*)Cbase + (size_t)blockIdx.z*lCb;

  constexpr int NKT = K_ / 32;
  __shared__ short As[64*AST];
  __shared__ short Bs[256*44];

  const int tid = threadIdx.x;
  const int row0 = blockIdx.x * 64;
  const int wave = tid >> 6, lane = tid & 63;
  const int wc = wave * 64;
  const int m16 = lane & 15, q = lane >> 4;

  const int ra = tid >> 2, ka = (tid & 3) * 8;
  const int cb = tid >> 2, kb = (tid & 3) * 8;

  f32x4 acc[4][4] = {};
  uint4 pb[4];

#define LOADB(k0_) { int kgb = (k0_) + kb;                                     \
    _Pragma("unroll")                                                          \
    for (int j = 0; j < 4; j++){                                               \
      int col = cb + j*64;                                                     \
      pb[j].x = pb[j].y = pb[j].z = pb[j].w = 0u;                              \
      if (col < Ncols) pb[j] = *(const uint4*)(Bt + col*Bts + kgb);            \
    } }

  LOADB(0);

  {
    const int grow = row0 + ra;
    uint4 tA[NKT];
    #pragma unroll
    for (int c = 0; c < NKT; c++){
      int kg = c*32 + ka;
      uint4 pa; pa.x = pa.y = pa.z = pa.w = 0u;
      if (grow < M){
        if (kg < KA){
          if (AF32){
            const float* ap = (const float*)A1 + grow*s1 + kg;
            float4 f0 = *(const float4*)ap;
            float4 f1 = *(const float4*)(ap + 4);
            pa.x = pk(f0.x, f0.y); pa.y = pk(f0.z, f0.w);
            pa.z = pk(f1.x, f1.y); pa.w = pk(f1.z, f1.w);
          } else {
            pa = *(const uint4*)((const bf16*)A1 + grow*s1 + kg);
          }
        } else if (kg - KA < KB){
          pa = *(const uint4*)(A2 + grow*s2 + (kg - KA));
        }
      }
      tA[c] = pa;
    }
    #pragma unroll
    for (int c = 0; c < NKT; c++)
      ldsst16(&As[ra*AST + c*32 + ka], tA[c]);
  }
  __syncthreads();

  #pragma unroll
  for (int ks = 0; ks < NKT; ks++){
    #pragma unroll
    for (int j = 0; j < 4; j++)
      ldsst16(&Bs[(cb + j*64)*44 + kb], pb[j]);
    __syncthreads();

    if (ks + 1 < NKT) LOADB((ks + 1)*32);

    bf16x8 af[4], bfv[4];
    #pragma unroll
    for (int rt = 0; rt < 4; rt++)
      af[rt] = ldsld8(&As[(rt*16 + m16)*AST + ks*32 + q*8]);
    #pragma unroll
    for (int ct = 0; ct < 4; ct++)
      bfv[ct] = ldsld8(&Bs[(wc + ct*16 + m16)*44 + q*8]);
    #pragma unroll
    for (int rt = 0; rt < 4; rt++)
      #pragma unroll
      for (int ct = 0; ct < 4; ct++)
        acc[rt][ct] = __builtin_amdgcn_mfma_f32_16x16x32_bf16(af[rt], bfv[ct], acc[rt][ct], 0, 0, 0);
    __syncthreads();
  }
#undef LOADB

  #pragma unroll
  for (int rt = 0; rt < 4; rt++){
    #pragma unroll
    for (int rr = 0; rr < 4; rr++){
      int row = row0 + rt*16 + q*4 + rr;
      if (row >= M) continue;
      #pragma unroll
      for (int ct = 0; ct < 4; ct++){
        int col = wc + ct*16 + m16;
        if (col >= Ncols) continue;
        float v = acc[rt][ct][rr] + (bias ? bias[col] : 0.f);
        if (OUTMODE == 1) ((float*)Cp)[row*Cstride + col] = v;
        else {
          if (col < 80) ((bf16*)Cp )[row*80 + col]      = f2b(v);
          else          ((bf16*)Cp2)[row*80 + col - 80] = f2b(v);
        }
      }
    }
  }
}

// ------------------------------------------------------------------ layer-0 GEMM1 (direct tiled-B, barrier-free)
__global__ __launch_bounds__(256) void k_g1(
    const float* __restrict__ h, const bf16* __restrict__ Bt1t,
    const float* __restrict__ bias1v,
    bf16* __restrict__ Ua, bf16* __restrict__ Ub)
{
  __shared__ short hA[32*100];   // 6,400 B
  const int tid = threadIdx.x;
  const int row0 = blockIdx.x * 32;
  const int wave = tid >> 6, lane = tid & 63;
  const int wc = wave * 64;
  const int m16 = lane & 15, q = lane >> 4;
  const int ra = tid >> 3, ka0 = (tid & 7) * 8;

  // stage h rows (f32->bf16); zero pad k in [80,96)
  {
    int grow = row0 + ra;
    #pragma unroll
    for (int c = 0; c < 2; c++){
      int kg = ka0 + c*64;
      if (kg < 96){
        uint4 pa; pa.x = pa.y = pa.z = pa.w = 0u;
        if (kg < 80 && grow < NN){
          const float* ap = h + grow*80 + kg;
          float4 f0 = *(const float4*)ap, f1 = *(const float4*)(ap + 4);
          pa.x = pk(f0.x, f0.y); pa.y = pk(f0.z, f0.w);
          pa.z = pk(f1.x, f1.y); pa.w = pk(f1.z, f1.w);
        }
        ldsst16(&hA[ra*100 + kg], pa);
      }
    }
  }
  __syncthreads();

  const bf16* bp1[4];
  #pragma unroll
  for (int ct = 0; ct < 4; ct++){
    int col = wc + ct*16 + m16;
    if (col >= 160) col = 0;
    bp1[ct] = Bt1t + col*32 + q*8;
  }
  f32x4 acc[2][4] = {};
  #pragma unroll
  for (int ks = 0; ks < 3; ks++){
    bf16x8 bfv[4], af[2];
    #pragma unroll
    for (int ct = 0; ct < 4; ct++)
      bfv[ct] = *(const bf16x8*)(bp1[ct] + ks*5120);
    #pragma unroll
    for (int rt = 0; rt < 2; rt++)
      af[rt] = ldsld8(&hA[(rt*16 + m16)*100 + ks*32 + q*8]);
    #pragma unroll
    for (int rt = 0; rt < 2; rt++)
      #pragma unroll
      for (int ct = 0; ct < 4; ct++)
        acc[rt][ct] = __builtin_amdgcn_mfma_f32_16x16x32_bf16(af[rt], bfv[ct], acc[rt][ct], 0, 0, 0);
  }
  #pragma unroll
  for (int rt = 0; rt < 2; rt++){
    #pragma unroll
    for (int rr = 0; rr < 4; rr++){
      int row = row0 + rt*16 + q*4 + rr;
      if (row >= NN) continue;
      #pragma unroll
      for (int ct = 0; ct < 4; ct++){
        int col = wc + ct*16 + m16;
        if (col >= 160) continue;
        float v = acc[rt][ct][rr] + bias1v[col];
        if (col < 80) Ua[row*80 + col]      = f2b(v);
        else          Ub[row*80 + col - 80] = f2b(v);
      }
    }
  }
}

// ------------------------------------------------------------------ fully-fused layer: agg + GEMM2 + epilogue + next GEMM1
// Aggregation fused with k_agg's EXACT per-thread footprint (16 f32: 4
// features x 4 stats; r6's spill was 80 f32) and a SINGLE edge walk (r9's
// thrash was 5 passes): 3 sub-rounds of (12|12|8 nodes x 20 threads), each
// neighbor row consumed fully (20 x 8B). Stats written straight into the LDS
// A-panel at k in [80,400). Eliminates the agg array (58MB/layer) + 4
// dispatches. U ping-pong (Uar/Ubr read, tail writes Uaw/Ubw) - r8 scheme.
__global__ __launch_bounds__(256) void k_g2(
    const float* __restrict__ h,
    const bf16* __restrict__ Uar, const bf16* __restrict__ Ubr,
    const int* __restrict__ rowptr, const int* __restrict__ colidx,
    const bf16* __restrict__ Bt, const float* __restrict__ bias2v,
    const float* __restrict__ scf, const float* __restrict__ invf,
    float* __restrict__ hp,
    const bf16* __restrict__ Bt1n, const float* __restrict__ bias1n,
    bf16* __restrict__ Uaw, bf16* __restrict__ Ubw)
{
  constexpr int AST = 420, NKT = 13;
  __shared__ short As[32*AST];   // 26,880 B
  __shared__ int nrp[33];
  bf16* eL = (bf16*)As;                 // epilogue staging 32x248 (15,872 B)
  bf16* hA = (bf16*)(As + 8192);        // h_new panel 32x100 (bytes 16,384..22,784)

  const int tid = threadIdx.x;
  const int row0 = blockIdx.x * 32;
  const int wave = tid >> 6, lane = tid & 63;
  const int wc = wave * 64;
  const int m16 = lane & 15, q = lane >> 4;
  const int ra = tid >> 3;           // 32 rows, 8 threads/row
  const int ka0 = (tid & 7) * 8;     // chunk start; stride 64 shorts

  // ---- rowptr slice
  if (tid < 33){
    int n = row0 + tid;
    nrp[tid] = rowptr[n < NN ? n : NN];
  }

  // ---- stage h rows into As k<80 (f32->bf16); zero pad k in [400,416)
  {
    const int grow = row0 + ra;
    #pragma unroll
    for (int c = 0; c < 7; c++){
      int kg = ka0 + c*64;
      if (kg < 80){
        uint4 pa; pa.x = pa.y = pa.z = pa.w = 0u;
        if (grow < NN){
          const float* ap = h + grow*80 + kg;
          float4 f0 = *(const float4*)ap;
          float4 f1 = *(const float4*)(ap + 4);
          pa.x = pk(f0.x, f0.y); pa.y = pk(f0.z, f0.w);
          pa.z = pk(f1.x, f1.y); pa.w = pk(f1.z, f1.w);
        }
        ldsst16(&As[ra*AST + kg], pa);
      } else if (kg >= 400 && kg < 416){
        uint4 z; z.x = z.y = z.z = z.w = 0u;
        ldsst16(&As[ra*AST + kg], z);
      }
    }
  }
  __syncthreads();   // nrp visible (h-panel writes don't conflict with stats)

  // ---- fused PNA aggregation: 3 sub-rounds x (12 nodes x 20 threads x 4 feat)
  {
    int s20 = tid / 20;            // node slot within sub-round (inactive >= 12)
    int fo = (tid - s20*20) * 4;   // feature offset
#define ACC2(w, o) { \
    float b0 = __uint_as_float((w) << 16); \
    float b1 = __uint_as_float((w) & 0xffff0000u); \
    sb[o] += b0; sq[o] += b0*b0; mn[o] = fminf(mn[o],b0); mx[o] = fmaxf(mx[o],b0); \
    sb[o+1] += b1; sq[o+1] += b1*b1; mn[o+1] = fminf(mn[o+1],b1); mx[o+1] = fmaxf(mx[o+1],b1); }
    #pragma unroll 1
    for (int rnd = 0; rnd < 3; rnd++){
      int slot = rnd*12 + s20;
      if (s20 < 12 && slot < 32){
        int n = row0 + slot;
        short* st = &As[slot*AST + 80 + fo];
        if (n < NN){
          int rs = nrp[slot], re = nrp[slot+1];
          int deg = re - rs;
          float a[4];
          {
            uint2 ua = *(const uint2*)(Uar + n*80 + fo);
            a[0] = __uint_as_float(ua.x << 16);
            a[1] = __uint_as_float(ua.x & 0xffff0000u);
            a[2] = __uint_as_float(ua.y << 16);
            a[3] = __uint_as_float(ua.y & 0xffff0000u);
          }
          float sb[4] = {0.f,0.f,0.f,0.f}, sq[4] = {0.f,0.f,0.f,0.f};
          float mn[4] = {1e30f,1e30f,1e30f,1e30f}, mx[4] = {-1e30f,-1e30f,-1e30f,-1e30f};
          for (int e = rs; e < re; e += 16){
            int cnt = re - e; if (cnt > 16) cnt = 16;
            int sx[16];
            #pragma unroll
            for (int j = 0; j < 16; j++) sx[j] = (j < cnt) ? colidx[e + j] : sx[0];
            uint2 u[16];
            #pragma unroll
            for (int j = 0; j < 16; j++) u[j] = *(const uint2*)(Ubr + sx[j]*80 + fo);
            #pragma unroll
            for (int j = 0; j < 16; j++){
              if (j < cnt){ ACC2(u[j].x, 0); ACC2(u[j].y, 2); }
            }
          }
          float degc = (float)(deg > 0 ? deg : 1);
          float inv = 1.f/degc;
          float dm = (float)deg;
          float mean[4], lo[4], hi[4], sd[4];
          #pragma unroll
          for (int i = 0; i < 4; i++){
            float av = a[i];
            mean[i] = (dm*av + sb[i])*inv;
            float vv = (dm*av*av + 2.f*av*sb[i] + sq[i])*inv - mean[i]*mean[i];
            sd[i] = sqrtf(fmaxf(vv, 0.f) + 1e-5f);
            lo[i] = deg > 0 ? av + mn[i] : 0.f;
            hi[i] = deg > 0 ? av + mx[i] : 0.f;
          }
          *(uint2*)(st)       = make_uint2(pk(mean[0],mean[1]), pk(mean[2],mean[3]));
          *(uint2*)(st +  80) = make_uint2(pk(lo[0],lo[1]),     pk(lo[2],lo[3]));
          *(uint2*)(st + 160) = make_uint2(pk(hi[0],hi[1]),     pk(hi[2],hi[3]));
          *(uint2*)(st + 240) = make_uint2(pk(sd[0],sd[1]),     pk(sd[2],sd[3]));
        } else {
          uint2 z = make_uint2(0u, 0u);
          *(uint2*)(st)       = z;
          *(uint2*)(st +  80) = z;
          *(uint2*)(st + 160) = z;
          *(uint2*)(st + 240) = z;
        }
      }
    }
#undef ACC2
  }

  // ---- per-lane tiled-B base pointers (OOB cols clamped; their acc unused)
  const bf16* bp[4];
  #pragma unroll
  for (int ct = 0; ct < 4; ct++){
    int col = wc + ct*16 + m16;
    if (col >= 240) col = 0;
    bp[ct] = Bt + col*32 + q*8;
  }
  __syncthreads();   // full A panel (h + stats + pad) ready

  f32x4 acc[2][4] = {};

  // ---- barrier-free K loop: direct-global B frags (contiguous 1KB/wave/frag)
  #pragma unroll
  for (int ks = 0; ks < NKT; ks++){
    bf16x8 bfv[4], af[2];
    #pragma unroll
    for (int ct = 0; ct < 4; ct++)
      bfv[ct] = *(const bf16x8*)(bp[ct] + ks*7680);
    #pragma unroll
    for (int rt = 0; rt < 2; rt++)
      af[rt] = ldsld8(&As[(rt*16 + m16)*AST + ks*32 + q*8]);
    #pragma unroll
    for (int rt = 0; rt < 2; rt++)
      #pragma unroll
      for (int ct = 0; ct < 4; ct++)
        acc[rt][ct] = __builtin_amdgcn_mfma_f32_16x16x32_bf16(af[rt], bfv[ct], acc[rt][ct], 0, 0, 0);
  }
  __syncthreads();   // all waves done reading As before eL overwrite

  // ---- epilogue: stage P|Q|R in eL
  #pragma unroll
  for (int rt = 0; rt < 2; rt++){
    #pragma unroll
    for (int ct = 0; ct < 4; ct++){
      int col = wc + ct*16 + m16;
      if (col >= 240) continue;
      #pragma unroll
      for (int rr = 0; rr < 4; rr++){
        int r = rt*16 + q*4 + rr;
        eL[r*248 + col] = f2b(acc[rt][ct][rr]);
      }
    }
  }
  __syncthreads();

  // ---- combine -> h_new; write global f32 + LDS bf16 panel
  #pragma unroll
  for (int i = 0; i < 10; i++){
    int idx = tid + i*256;
    int r = idx / 80, c = idx - r*80;
    int row = row0 + r;
    if (row < NN){
      float P = b2f(eL[r*248 + c]);
      float Q = b2f(eL[r*248 + 80 + c]);
      float R = b2f(eL[r*248 + 160 + c]);
      float o = P + scf[row]*Q + invf[row]*R + bias2v[c];
      float hn = hp[row*80 + c] + fmaxf(o, 0.f);
      hp[row*80 + c] = hn;
      if (Bt1n) hA[r*100 + c] = f2b(hn);
    } else if (Bt1n && idx < 32*80){
      hA[r*100 + c] = f2b(0.f);   // tail rows: defined values for mini-GEMM
    }
  }
  if (Bt1n && tid < 128){
    // zero pad k in [80,96)
    int r = tid >> 2, off = 80 + (tid & 3)*4;
    *(uint2*)&hA[r*100 + off] = make_uint2(0u, 0u);
  }
  __syncthreads();

  // ---- mini-GEMM: U = h_new @ Bt1[next] (tiled-B, barrier-free)
  if (Bt1n){
    const bf16* bp1[4];
    #pragma unroll
    for (int ct = 0; ct < 4; ct++){
      int col = wc + ct*16 + m16;
      if (col >= 160) col = 0;
      bp1[ct] = Bt1n + col*32 + q*8;
    }
    f32x4 acc2[2][4] = {};
    #pragma unroll
    for (int ks = 0; ks < 3; ks++){
      bf16x8 bfv[4], af[2];
      #pragma unroll
      for (int ct = 0; ct < 4; ct++)
        bfv[ct] = *(const bf16x8*)(bp1[ct] + ks*5120);
      #pragma unroll
      for (int rt = 0; rt < 2; rt++)
        af[rt] = ldsld8((const short*)hA + (rt*16 + m16)*100 + ks*32 + q*8);
      #pragma unroll
      for (int rt = 0; rt < 2; rt++)
        #pragma unroll
        for (int ct = 0; ct < 4; ct++)
          acc2[rt][ct] = __builtin_amdgcn_mfma_f32_16x16x32_bf16(af[rt], bfv[ct], acc2[rt][ct], 0, 0, 0);
    }
    #pragma unroll
    for (int rt = 0; rt < 2; rt++){
      #pragma unroll
      for (int rr = 0; rr < 4; rr++){
        int row = row0 + rt*16 + q*4 + rr;
        if (row >= NN) continue;
        #pragma unroll
        for (int ct = 0; ct < 4; ct++){
          int col = wc + ct*16 + m16;
          if (col >= 160) continue;
          float v = acc2[rt][ct][rr] + bias1n[col];
          if (col < 80) Uaw[row*80 + col]      = f2b(v);
          else          Ubw[row*80 + col - 80] = f2b(v);
        }
      }
    }
  }
}

// ------------------------------------------------------------------ fused mean-pool + head
__global__ __launch_bounds__(128) void k_poolmlp(const float* __restrict__ h,
                        const int* __restrict__ batch,
                        const void* __restrict__ mlpW, const void* __restrict__ mlpb,
                        const int* __restrict__ flag, void* __restrict__ outp){
  __shared__ float sred[128];
  __shared__ int sb[2];
  int g = blockIdx.x;
  int t = threadIdx.x;
  if (t < 2){
    int target = g + t;
    int lo = 0, hi = NN;
    while (lo < hi){ int mid = (lo + hi) >> 1; if (batch[mid] < target) lo = mid + 1; else hi = mid; }
    sb[t] = lo;
  }
  __syncthreads();
  int lo = sb[0], hi = sb[1];
  float s = 0.f;
  if (t < 80)
    for (int n = lo; n < hi; n++) s += h[n*80 + t];
  int fl = flag[0];
  float wv = (t < 80) ? rdw(mlpW, t, fl) : 0.f;
  sred[t] = s * wv;
  __syncthreads();
  for (int off = 64; off > 0; off >>= 1){
    if (t < off) sred[t] += sred[t + off];
    __syncthreads();
  }
  if (t == 0){
    float cnt = (float)(hi - lo); if (cnt < 1.f) cnt = 1.f;
    float r = sred[0]/cnt + rdw(mlpb, 0, fl);
    if (fl) ((float*)outp)[g] = r;
    else    ((bf16*)outp)[g] = f2b(r);
  }
}

// ------------------------------------------------------------------ launch
extern "C" void kernel_launch(void* const* d_in, const int* in_sizes, int n_in,
                              void* d_out, int out_size, void* d_ws, size_t ws_size,
                              hipStream_t stream)
{
  const int*  x     = (const int*) d_in[0];
  const int*  ei    = (const int*) d_in[1];
  const int*  batch = (const int*) d_in[2];
  const void* avgp  = d_in[3];
  const void* aemb  = d_in[4];
  const void* preW  = d_in[5];
  const void* preb  = d_in[6];
  const void* postW = d_in[7];
  const void* postb = d_in[8];
  const void* linW  = d_in[9];
  const void* linb  = d_in[10];
  const void* bng   = d_in[11];
  const void* bnb   = d_in[12];
  const void* bnm   = d_in[13];
  const void* bnv   = d_in[14];
  const void* mlpW  = d_in[15];
  const void* mlpb  = d_in[16];

  char* w = (char*)d_ws;
  int*   flag   = (int*)  (w + 400000);       //       256  (zeroed)
  int*   rowptr = (int*)  (w + 401280);       //   200,064
  int*   colidx = (int*)  (w + 601344);       // 3,200,000
  float* scf    = (float*)(w + 3801344);      //   200,000
  float* invf   = (float*)(w + 4001344);      //   200,000
  float* bias1  = (float*)(w + 4201344);      //     2,560
  float* bias2  = (float*)(w + 4203904);      //     1,280
  bf16*  Btl    = (bf16*) (w + 4205184);      //    61,440
  bf16*  Bt1    = (bf16*) (w + 4266624);      //   122,880  (tiled layout)
  bf16*  Bt2    = (bf16*) (w + 4389504);      //   798,720  (tiled layout)
  float* h      = (float*)(w + 5188224);      // 16,000,000  f32 [N,80]
  bf16*  UaA    = (bf16*) (w + 21188224);     //  8,000,000  bf16 [N,80]
  bf16*  UbA    = (bf16*) (w + 29188224);     //  8,000,000  bf16 [N,80]
  bf16*  UaB    = (bf16*) (w + 45188224);     //  8,000,000  (ping-pong, ex-agg)
  bf16*  UbB    = (bf16*) (w + 53188224);     //  8,000,000
  // pre-loop overlays (consumed before layer 0):
  bf16*  pwb    = (bf16*) (w + 61188224);     //   665,600
  float* Wf     = (float*)(w + 61853824);     // 1,331,200
  int* staging  = (int*)  (w + 63185024);     // 3,200,000
  int* chunkcnt = (int*)  (w + 66385024);     //   613,088  [NCH][NBUCK]
  int* btotal   = (int*)  (w + 66998112);     //     3,128
  int* bbase    = (int*)  (w + 67001240);     //     3,136  (NBUCK+1)
  // total 77,188,224 B (end 67,004,376)

  k_zero <<<1, 256, 0, stream>>>(flag, 64);
  k_probe<<<16, 256, 0, stream>>>(aemb, flag);

  // atomic-free CSR build
  k_hist <<<NCH, 256, 0, stream>>>(ei, chunkcnt);
  k_cscan<<<NBUCK, 256, 0, stream>>>(chunkcnt, btotal);
  k_bscan<<<1, 256, 0, stream>>>(btotal, bbase);
  k_place<<<NCH, 256, 0, stream>>>(ei, chunkcnt, bbase, staging);

  k_prep_all<<<1662, 256, 0, stream>>>(preW, preb, postW, postb, linW, linb,
                                       bng, bnb, bnm, bnv, flag,
                                       pwb, Btl, Bt1, bias1, bias2);

  // Wf[i] = postW[i](bf16) @ Btl[i]^T   (f32 out)
  k_mgemm<0,1,96,100><<<dim3(17,1,4), 256, 0, stream>>>(
      pwb, 80, 80, nullptr, 0, 0,
      Btl, 96, 80, nullptr, Wf, nullptr, 80, 1040,
      166400, 15360, 332800);
  k_prep_Bt2<<<(4*240*416 + 255)/256, 256, 0, stream>>>(Wf, Bt2);

  k_atom <<<(NN*10 + 255)/256, 256, 0, stream>>>(x, aemb, flag, h);

  // fused rowptr/scf/invf + counting-sorted colidx
  k_csr<<<NBUCK, 256, 0, stream>>>(staging, bbase, avgp, flag, rowptr, scf, invf, colidx);

  const int gx2 = (NN + 31)/32;   // 1563
  // layer-0 GEMM1 (subsequent layers' GEMM1 are fused into k_g2's tail)
  k_g1<<<dim3(gx2,1,1), 256, 0, stream>>>(h, Bt1, bias1, UaA, UbA);
  for (int i = 0; i < 4; i++){
    const bf16* Uar = (i & 1) ? UaB : UaA;
    const bf16* Ubr = (i & 1) ? UbB : UbA;
    bf16* Uaw = (i & 1) ? UaA : UaB;
    bf16* Ubw = (i & 1) ? UbA : UbB;
    const bf16* nBt1 = (i < 3) ? (Bt1 + (i+1)*15360) : nullptr;
    const float* nb1 = (i < 3) ? (bias1 + (i+1)*160) : bias1;
    k_g2<<<dim3(gx2,1,1), 256, 0, stream>>>(
        h, Uar, Ubr, rowptr, colidx,
        Bt2 + i*99840, bias2 + i*80, scf, invf, h,
        nBt1, nb1, Uaw, Ubw);
  }

  k_poolmlp<<<NGR, 128, 0, stream>>>(h, batch, mlpW, mlpb, flag, d_out);
}

// Round 16
// 502.476 us; speedup vs baseline: 1.0420x; 1.0245x over previous
//
#include <hip/hip_runtime.h>
#include <hip/hip_bf16.h>

#define NN 50000
#define NE 800000
#define FD 80
#define NGR 1024
#define NF 9

// bucketed CSR sort (atomic-free counting sort)
#define BSH 6
#define NBUCK ((NN + 63) >> 6)     // 782 node-buckets of 64
#define CSH 12
#define NCH ((NE + 4095) >> 12)    // 196 edge-chunks of 4096
#define BCAP 2048

using bf16 = __hip_bfloat16;
typedef __attribute__((ext_vector_type(8))) short bf16x8;
typedef __attribute__((ext_vector_type(4))) float f32x4;

static __device__ __forceinline__ float b2f(bf16 v){ return __bfloat162float(v); }
static __device__ __forceinline__ bf16 f2b(float v){ return __float2bfloat16(v); }
static __device__ __forceinline__ float rdw(const void* p, int i, int fl){
  return fl ? ((const float*)p)[i] : b2f(((const bf16*)p)[i]);
}
static __device__ __forceinline__ unsigned pk(float a, float b){
  bf16 x = f2b(a), y = f2b(b);
  return (unsigned)*(unsigned short*)&x | ((unsigned)*(unsigned short*)&y << 16);
}
// 8B-granule LDS access (strides are 8B- but not 16B-aligned)
static __device__ __forceinline__ bf16x8 ldsld8(const short* p){
  union { bf16x8 v; uint2 u[2]; } r;
  r.u[0] = *(const uint2*)(p);
  r.u[1] = *(const uint2*)(p + 4);
  return r.v;
}
static __device__ __forceinline__ void ldsst16(short* p, uint4 v){
  *(uint2*)(p)     = make_uint2(v.x, v.y);
  *(uint2*)(p + 4) = make_uint2(v.z, v.w);
}

// ------------------------------------------------------------------ utility
__global__ void k_zero(int* __restrict__ p, int n){
  int t = blockIdx.x*256 + threadIdx.x;
  if (t < n) p[t] = 0;
}

__global__ void k_probe(const void* __restrict__ emb, int* __restrict__ flag){
  int t = blockIdx.x*256 + threadIdx.x;
  float v = b2f(((const bf16*)emb)[t]);
  if (!(fabsf(v) < 1e4f)) atomicOr(flag, 1);
}

// ------------------------------------------------------------------ fused weight prep
// Bt1/Bt2 in K-step-major FRAGMENT-TILED layout (r12 win): one wave's MFMA
// B-frag load is a contiguous 1KB segment (direct-global, no LDS staging).
__global__ __launch_bounds__(256) void k_prep_all(
    const void* __restrict__ preW, const void* __restrict__ preb,
    const void* __restrict__ postW, const void* __restrict__ postb,
    const void* __restrict__ linW, const void* __restrict__ linb,
    const void* __restrict__ bng, const void* __restrict__ bnb,
    const void* __restrict__ bnm, const void* __restrict__ bnv,
    const int* __restrict__ flag,
    bf16* __restrict__ pwb, bf16* __restrict__ Btl, bf16* __restrict__ Bt1,
    float* __restrict__ bias1, float* __restrict__ bias2)
{
  int fl = flag[0];
  int b = blockIdx.x;
  if (b < 1300){
    int t = b*256 + threadIdx.x;
    pwb[t] = f2b(rdw(postW, t, fl));
  } else if (b < 1420){
    int t = (b - 1300)*256 + threadIdx.x;
    int j = t % 96, c = (t/96) % 80, i = t/(96*80);
    float v = 0.f;
    if (j < 80){
      float gs = rdw(bng, i*80 + c, fl) * rsqrtf(rdw(bnv, i*80 + c, fl) + 1e-5f);
      v = rdw(linW, i*6400 + j*80 + c, fl) * gs;
    }
    Btl[t] = f2b(v);
  } else if (b < 1660){
    int t = (b - 1420)*256 + threadIdx.x;
    int k = t % 96, c = (t/96) % 160, i = t/(96*160);
    float v = 0.f;
    if (k < 80)
      v = (c < 80) ? rdw(preW, (i*160 + k)*80 + c, fl)
                   : rdw(preW, (i*160 + 80 + k)*80 + (c - 80), fl);
    int of = ((k >> 5)*160 + c)*32 + (k & 31);
    Bt1[i*15360 + of] = f2b(v);
    if (k == 0) bias1[i*160 + c] = (c < 80) ? rdw(preb, i*80 + c, fl) : 0.f;
  } else {
    int t = (b - 1660)*256 + threadIdx.x;
    if (t >= 4*80) return;
    int i = t / 80, f = t - i*80;
    float s = 0.f;
    for (int j = 0; j < 80; j++)
      s += rdw(postb, i*80 + j, fl) * rdw(linW, (i*80 + j)*80 + f, fl);
    s += rdw(linb, t, fl);
    float gs = rdw(bng, t, fl) * rsqrtf(rdw(bnv, t, fl) + 1e-5f);
    bias2[t] = (s - rdw(bnm, t, fl)) * gs + rdw(bnb, t, fl);
  }
}

// Bt2 in fragment-tiled layout: element (c,k) at ks*240*32 + c*32 + (k&31).
__global__ void k_prep_Bt2(const float* __restrict__ Wf, bf16* __restrict__ Bt2){
  int t = blockIdx.x*256 + threadIdx.x;
  if (t >= 4*240*416) return;
  int k = t % 416;
  int c = (t/416) % 240;
  int i = t/(416*240);
  float v = 0.f;
  if (k < 400){
    int blk = c/80, f = c - blk*80;
    if (blk == 0) v = Wf[(i*1040 + k)*80 + f];
    else if (k >= 80){
      int row = (blk == 1 ? 400 : 720) + (k - 80);
      v = Wf[(i*1040 + row)*80 + f];
    }
  }
  int of = (k >> 5)*7680 + c*32 + (k & 31);
  Bt2[i*99840 + of] = f2b(v);
}

// ------------------------------------------------------------------ graph prep
__global__ void k_atom(const int* __restrict__ x, const void* __restrict__ emb,
                       const int* __restrict__ flag, float* __restrict__ h){
  int fl = flag[0];
  int gid = blockIdx.x*256 + threadIdx.x;
  if (gid >= NN*10) return;
  int n = gid / 10, fb = gid - n*10;
  int f0 = fb*8;
  int xr[NF];
  #pragma unroll
  for (int c = 0; c < NF; c++) xr[c] = x[n*NF + c];
  float s[8] = {0.f,0.f,0.f,0.f,0.f,0.f,0.f,0.f};
  if (fl){
    #pragma unroll
    for (int c = 0; c < NF; c++){
      const float* ep = (const float*)emb + (c*119 + xr[c])*80 + f0;
      float4 a = *(const float4*)ep, b = *(const float4*)(ep + 4);
      s[0]+=a.x; s[1]+=a.y; s[2]+=a.z; s[3]+=a.w;
      s[4]+=b.x; s[5]+=b.y; s[6]+=b.z; s[7]+=b.w;
    }
  } else {
    #pragma unroll
    for (int c = 0; c < NF; c++){
      const bf16* ep = (const bf16*)emb + (c*119 + xr[c])*80 + f0;
      uint4 u = *(const uint4*)ep;
      s[0]+=__uint_as_float(u.x<<16); s[1]+=__uint_as_float(u.x&0xffff0000u);
      s[2]+=__uint_as_float(u.y<<16); s[3]+=__uint_as_float(u.y&0xffff0000u);
      s[4]+=__uint_as_float(u.z<<16); s[5]+=__uint_as_float(u.z&0xffff0000u);
      s[6]+=__uint_as_float(u.w<<16); s[7]+=__uint_as_float(u.w&0xffff0000u);
    }
  }
  float* hp = h + n*80 + f0;
  *(float4*)hp       = make_float4(s[0],s[1],s[2],s[3]);
  *(float4*)(hp + 4) = make_float4(s[4],s[5],s[6],s[7]);
}

// ---- atomic-free CSR build: hist -> cscan -> bscan -> place -> csr ----

__global__ __launch_bounds__(256) void k_hist(const int* __restrict__ ei,
                                              int* __restrict__ chunkcnt){
  __shared__ int hist[NBUCK];
  int c = blockIdx.x, t = threadIdx.x;
  for (int i = t; i < NBUCK; i += 256) hist[i] = 0;
  __syncthreads();
  #pragma unroll
  for (int j = 0; j < 16; j++){
    int e = (c << CSH) + j*256 + t;
    if (e < NE) atomicAdd(&hist[ei[NE + e] >> BSH], 1);
  }
  __syncthreads();
  for (int i = t; i < NBUCK; i += 256) chunkcnt[c*NBUCK + i] = hist[i];
}

__global__ __launch_bounds__(256) void k_cscan(int* __restrict__ chunkcnt,
                                               int* __restrict__ btotal){
  __shared__ int buf[256];
  int b = blockIdx.x, t = threadIdx.x;
  int v[4]; int s = 0;
  #pragma unroll
  for (int j = 0; j < 4; j++){
    int c = t*4 + j;
    v[j] = (c < NCH) ? chunkcnt[c*NBUCK + b] : 0;
    s += v[j];
  }
  buf[t] = s;
  __syncthreads();
  for (int off = 1; off < 256; off <<= 1){
    int xv = (t >= off) ? buf[t - off] : 0;
    __syncthreads();
    buf[t] += xv;
    __syncthreads();
  }
  int excl = buf[t] - s;
  #pragma unroll
  for (int j = 0; j < 4; j++){
    int c = t*4 + j;
    if (c < NCH){ chunkcnt[c*NBUCK + b] = excl; excl += v[j]; }
  }
  if (t == 255) btotal[b] = buf[255];
}

__global__ __launch_bounds__(256) void k_bscan(const int* __restrict__ btotal,
                                               int* __restrict__ bbase){
  __shared__ int buf[256];
  int t = threadIdx.x;
  int v[4]; int s = 0;
  #pragma unroll
  for (int j = 0; j < 4; j++){
    int c = t*4 + j;
    v[j] = (c < NBUCK) ? btotal[c] : 0;
    s += v[j];
  }
  buf[t] = s;
  __syncthreads();
  for (int off = 1; off < 256; off <<= 1){
    int xv = (t >= off) ? buf[t - off] : 0;
    __syncthreads();
    buf[t] += xv;
    __syncthreads();
  }
  int excl = buf[t] - s;
  #pragma unroll
  for (int j = 0; j < 4; j++){
    int c = t*4 + j;
    if (c < NBUCK){ bbase[c] = excl; excl += v[j]; }
  }
  if (t == 255) bbase[NBUCK] = buf[255];
}

__global__ __launch_bounds__(256) void k_place(const int* __restrict__ ei,
                        const int* __restrict__ chunkcnt, const int* __restrict__ bbase,
                        int* __restrict__ staging){
  __shared__ int basep[NBUCK];
  __shared__ int cur[NBUCK];
  int c = blockIdx.x, t = threadIdx.x;
  for (int i = t; i < NBUCK; i += 256){
    basep[i] = chunkcnt[c*NBUCK + i] + bbase[i];
    cur[i] = 0;
  }
  __syncthreads();
  #pragma unroll
  for (int j = 0; j < 16; j++){
    int e = (c << CSH) + j*256 + t;
    if (e < NE){
      int d = ei[NE + e], s = ei[e];
      int b = d >> BSH;
      int r = atomicAdd(&cur[b], 1);
      staging[basep[b] + r] = (s << BSH) | (d & 63);
    }
  }
}

__global__ __launch_bounds__(256) void k_csr(const int* __restrict__ staging,
                        const int* __restrict__ bbase, const void* __restrict__ avgp,
                        const int* __restrict__ flag, int* __restrict__ rowptr,
                        float* __restrict__ scf, float* __restrict__ invf,
                        int* __restrict__ colidx){
  __shared__ int lcnt[64], lrp[64], lcur[64];
  __shared__ int colbuf[BCAP];
  int b = blockIdx.x, t = threadIdx.x;
  int base = bbase[b];
  int cnt  = bbase[b+1] - base;
  if (t < 64){ lcnt[t] = 0; lcur[t] = 0; }
  __syncthreads();
  for (int i = t; i < cnt; i += 256)
    atomicAdd(&lcnt[staging[base + i] & 63], 1);
  __syncthreads();
  if (t < 64) lrp[t] = lcnt[t];
  __syncthreads();
  for (int off = 1; off < 64; off <<= 1){
    int xv = (t < 64 && t >= off) ? lrp[t - off] : 0;
    __syncthreads();
    if (t < 64) lrp[t] += xv;
    __syncthreads();
  }
  int n0 = b << BSH;
  if (t < 64){
    int ex = lrp[t] - lcnt[t];
    lrp[t] = ex;
    int n = n0 + t;
    if (n < NN){
      rowptr[n] = base + ex;
      float degc = (float)(lcnt[t] > 0 ? lcnt[t] : 1);
      float logd = logf(degc + 1.f);
      float avg = rdw(avgp, 0, flag[0]);
      scf[n] = logd / avg;
      invf[n] = avg / logd;
    }
  }
  if (b == 0 && t == 0) rowptr[NN] = NE;
  __syncthreads();
  if (cnt <= BCAP){
    for (int i = t; i < cnt; i += 256){
      int v = staging[base + i];
      int l = v & 63;
      int pos = lrp[l] + atomicAdd(&lcur[l], 1);
      colbuf[pos] = v >> BSH;
    }
    __syncthreads();
    for (int i = t; i < cnt; i += 256)
      colidx[base + i] = colbuf[i];
  } else {
    for (int i = t; i < cnt; i += 256){
      int v = staging[base + i];
      int l = v & 63;
      int pos = lrp[l] + atomicAdd(&lcur[l], 1);
      colidx[base + pos] = v >> BSH;
    }
  }
}

// ------------------------------------------------------------------ MFMA GEMM (r4 structure; Wf only)
template<int AF32, int OUTMODE, int K_, int AST>
__global__ __launch_bounds__(256) void k_mgemm(
    const void* __restrict__ A1p, int s1, int KA,
    const bf16* __restrict__ A2, int s2, int KB,
    const bf16* __restrict__ Btp, int Bts, int Ncols,
    const float* __restrict__ bias,
    void* __restrict__ Cbase, void* __restrict__ Cp2, int Cstride, int M,
    int lA1b, int lBtb, int lCb)
{
  const void* A1 = (const char*)A1p + (size_t)blockIdx.z*lA1b;
  const bf16* Bt = (const bf16*)((const char*)Btp + (size_t)blockIdx.z*lBtb);
  void* Cp = (char*)Cbase + (size_t)blockIdx.z*lCb;

  constexpr int NKT = K_ / 32;
  __shared__ short As[64*AST];
  __shared__ short Bs[256*44];

  const int tid = threadIdx.x;
  const int row0 = blockIdx.x * 64;
  const int wave = tid >> 6, lane = tid & 63;
  const int wc = wave * 64;
  const int m16 = lane & 15, q = lane >> 4;

  const int ra = tid >> 2, ka = (tid & 3) * 8;
  const int cb = tid >> 2, kb = (tid & 3) * 8;

  f32x4 acc[4][4] = {};
  uint4 pb[4];

#define LOADB(k0_) { int kgb = (k0_) + kb;                                     \
    _Pragma("unroll")                                                          \
    for (int j = 0; j < 4; j++){                                               \
      int col = cb + j*64;                                                     \
      pb[j].x = pb[j].y = pb[j].z = pb[j].w = 0u;                              \
      if (col < Ncols) pb[j] = *(const uint4*)(Bt + col*Bts + kgb);            \
    } }

  LOADB(0);

  {
    const int grow = row0 + ra;
    uint4 tA[NKT];
    #pragma unroll
    for (int c = 0; c < NKT; c++){
      int kg = c*32 + ka;
      uint4 pa; pa.x = pa.y = pa.z = pa.w = 0u;
      if (grow < M){
        if (kg < KA){
          if (AF32){
            const float* ap = (const float*)A1 + grow*s1 + kg;
            float4 f0 = *(const float4*)ap;
            float4 f1 = *(const float4*)(ap + 4);
            pa.x = pk(f0.x, f0.y); pa.y = pk(f0.z, f0.w);
            pa.z = pk(f1.x, f1.y); pa.w = pk(f1.z, f1.w);
          } else {
            pa = *(const uint4*)((const bf16*)A1 + grow*s1 + kg);
          }
        } else if (kg - KA < KB){
          pa = *(const uint4*)(A2 + grow*s2 + (kg - KA));
        }
      }
      tA[c] = pa;
    }
    #pragma unroll
    for (int c = 0; c < NKT; c++)
      ldsst16(&As[ra*AST + c*32 + ka], tA[c]);
  }
  __syncthreads();

  #pragma unroll
  for (int ks = 0; ks < NKT; ks++){
    #pragma unroll
    for (int j = 0; j < 4; j++)
      ldsst16(&Bs[(cb + j*64)*44 + kb], pb[j]);
    __syncthreads();

    if (ks + 1 < NKT) LOADB((ks + 1)*32);

    bf16x8 af[4], bfv[4];
    #pragma unroll
    for (int rt = 0; rt < 4; rt++)
      af[rt] = ldsld8(&As[(rt*16 + m16)*AST + ks*32 + q*8]);
    #pragma unroll
    for (int ct = 0; ct < 4; ct++)
      bfv[ct] = ldsld8(&Bs[(wc + ct*16 + m16)*44 + q*8]);
    #pragma unroll
    for (int rt = 0; rt < 4; rt++)
      #pragma unroll
      for (int ct = 0; ct < 4; ct++)
        acc[rt][ct] = __builtin_amdgcn_mfma_f32_16x16x32_bf16(af[rt], bfv[ct], acc[rt][ct], 0, 0, 0);
    __syncthreads();
  }
#undef LOADB

  #pragma unroll
  for (int rt = 0; rt < 4; rt++){
    #pragma unroll
    for (int rr = 0; rr < 4; rr++){
      int row = row0 + rt*16 + q*4 + rr;
      if (row >= M) continue;
      #pragma unroll
      for (int ct = 0; ct < 4; ct++){
        int col = wc + ct*16 + m16;
        if (col >= Ncols) continue;
        float v = acc[rt][ct][rr] + (bias ? bias[col] : 0.f);
        if (OUTMODE == 1) ((float*)Cp)[row*Cstride + col] = v;
        else {
          if (col < 80) ((bf16*)Cp )[row*80 + col]      = f2b(v);
          else          ((bf16*)Cp2)[row*80 + col - 80] = f2b(v);
        }
      }
    }
  }
}

// ------------------------------------------------------------------ layer-0 GEMM1 (direct tiled-B, barrier-free)
__global__ __launch_bounds__(256) void k_g1(
    const float* __restrict__ h, const bf16* __restrict__ Bt1t,
    const float* __restrict__ bias1v,
    bf16* __restrict__ Ua, bf16* __restrict__ Ub)
{
  __shared__ short hA[32*100];   // 6,400 B
  const int tid = threadIdx.x;
  const int row0 = blockIdx.x * 32;
  const int wave = tid >> 6, lane = tid & 63;
  const int wc = wave * 64;
  const int m16 = lane & 15, q = lane >> 4;
  const int ra = tid >> 3, ka0 = (tid & 7) * 8;

  // stage h rows (f32->bf16); zero pad k in [80,96)
  {
    int grow = row0 + ra;
    #pragma unroll
    for (int c = 0; c < 2; c++){
      int kg = ka0 + c*64;
      if (kg < 96){
        uint4 pa; pa.x = pa.y = pa.z = pa.w = 0u;
        if (kg < 80 && grow < NN){
          const float* ap = h + grow*80 + kg;
          float4 f0 = *(const float4*)ap, f1 = *(const float4*)(ap + 4);
          pa.x = pk(f0.x, f0.y); pa.y = pk(f0.z, f0.w);
          pa.z = pk(f1.x, f1.y); pa.w = pk(f1.z, f1.w);
        }
        ldsst16(&hA[ra*100 + kg], pa);
      }
    }
  }
  __syncthreads();

  const bf16* bp1[4];
  #pragma unroll
  for (int ct = 0; ct < 4; ct++){
    int col = wc + ct*16 + m16;
    if (col >= 160) col = 0;
    bp1[ct] = Bt1t + col*32 + q*8;
  }
  f32x4 acc[2][4] = {};
  #pragma unroll
  for (int ks = 0; ks < 3; ks++){
    bf16x8 bfv[4], af[2];
    #pragma unroll
    for (int ct = 0; ct < 4; ct++)
      bfv[ct] = *(const bf16x8*)(bp1[ct] + ks*5120);
    #pragma unroll
    for (int rt = 0; rt < 2; rt++)
      af[rt] = ldsld8(&hA[(rt*16 + m16)*100 + ks*32 + q*8]);
    #pragma unroll
    for (int rt = 0; rt < 2; rt++)
      #pragma unroll
      for (int ct = 0; ct < 4; ct++)
        acc[rt][ct] = __builtin_amdgcn_mfma_f32_16x16x32_bf16(af[rt], bfv[ct], acc[rt][ct], 0, 0, 0);
  }
  #pragma unroll
  for (int rt = 0; rt < 2; rt++){
    #pragma unroll
    for (int rr = 0; rr < 4; rr++){
      int row = row0 + rt*16 + q*4 + rr;
      if (row >= NN) continue;
      #pragma unroll
      for (int ct = 0; ct < 4; ct++){
        int col = wc + ct*16 + m16;
        if (col >= 160) continue;
        float v = acc[rt][ct][rr] + bias1v[col];
        if (col < 80) Ua[row*80 + col]      = f2b(v);
        else          Ub[row*80 + col - 80] = f2b(v);
      }
    }
  }
}

// ------------------------------------------------------------------ fully-fused layer: agg + GEMM2 + epilogue + next GEMM1
// r15 form (measured 514.8us best), with the aggregation moved to the TOP of
// the kernel: per-thread direct rowptr loads (no nrp LDS, no first barrier),
// so the 3 sub-rounds of long-latency random gathers are issued at kernel
// start and OVERLAP the h-panel's 16MB HBM streaming that follows. Disjoint
// As regions (agg: k in [80,400); staging: k<80 and [400,416)) -> single
// barrier before the K-loop.
__global__ __launch_bounds__(256) void k_g2(
    const float* __restrict__ h,
    const bf16* __restrict__ Uar, const bf16* __restrict__ Ubr,
    const int* __restrict__ rowptr, const int* __restrict__ colidx,
    const bf16* __restrict__ Bt, const float* __restrict__ bias2v,
    const float* __restrict__ scf, const float* __restrict__ invf,
    float* __restrict__ hp,
    const bf16* __restrict__ Bt1n, const float* __restrict__ bias1n,
    bf16* __restrict__ Uaw, bf16* __restrict__ Ubw)
{
  constexpr int AST = 420, NKT = 13;
  __shared__ short As[32*AST];   // 26,880 B
  bf16* eL = (bf16*)As;                 // epilogue staging 32x248 (15,872 B)
  bf16* hA = (bf16*)(As + 8192);        // h_new panel 32x100 (bytes 16,384..22,784)

  const int tid = threadIdx.x;
  const int row0 = blockIdx.x * 32;
  const int wave = tid >> 6, lane = tid & 63;
  const int wc = wave * 64;
  const int m16 = lane & 15, q = lane >> 4;
  const int ra = tid >> 3;           // 32 rows, 8 threads/row
  const int ka0 = (tid & 7) * 8;     // chunk start; stride 64 shorts

  // ---- fused PNA aggregation FIRST: 3 sub-rounds x (12 nodes x 20 thr x 4 feat)
  //      gathers issue at kernel start; h streaming below overlaps their latency
  {
    int s20 = tid / 20;            // node slot within sub-round (inactive >= 12)
    int fo = (tid - s20*20) * 4;   // feature offset
#define ACC2(w, o) { \
    float b0 = __uint_as_float((w) << 16); \
    float b1 = __uint_as_float((w) & 0xffff0000u); \
    sb[o] += b0; sq[o] += b0*b0; mn[o] = fminf(mn[o],b0); mx[o] = fmaxf(mx[o],b0); \
    sb[o+1] += b1; sq[o+1] += b1*b1; mn[o+1] = fminf(mn[o+1],b1); mx[o+1] = fmaxf(mx[o+1],b1); }
    #pragma unroll 1
    for (int rnd = 0; rnd < 3; rnd++){
      int slot = rnd*12 + s20;
      if (s20 < 12 && slot < 32){
        int n = row0 + slot;
        short* st = &As[slot*AST + 80 + fo];
        if (n < NN){
          int rs = rowptr[n], re = rowptr[n+1];   // broadcast within node group (L1)
          int deg = re - rs;
          float a[4];
          {
            uint2 ua = *(const uint2*)(Uar + n*80 + fo);
            a[0] = __uint_as_float(ua.x << 16);
            a[1] = __uint_as_float(ua.x & 0xffff0000u);
            a[2] = __uint_as_float(ua.y << 16);
            a[3] = __uint_as_float(ua.y & 0xffff0000u);
          }
          float sb[4] = {0.f,0.f,0.f,0.f}, sq[4] = {0.f,0.f,0.f,0.f};
          float mn[4] = {1e30f,1e30f,1e30f,1e30f}, mx[4] = {-1e30f,-1e30f,-1e30f,-1e30f};
          for (int e = rs; e < re; e += 16){
            int cnt = re - e; if (cnt > 16) cnt = 16;
            int sx[16];
            #pragma unroll
            for (int j = 0; j < 16; j++) sx[j] = (j < cnt) ? colidx[e + j] : sx[0];
            uint2 u[16];
            #pragma unroll
            for (int j = 0; j < 16; j++) u[j] = *(const uint2*)(Ubr + sx[j]*80 + fo);
            #pragma unroll
            for (int j = 0; j < 16; j++){
              if (j < cnt){ ACC2(u[j].x, 0); ACC2(u[j].y, 2); }
            }
          }
          float degc = (float)(deg > 0 ? deg : 1);
          float inv = 1.f/degc;
          float dm = (float)deg;
          float mean[4], lo[4], hi[4], sd[4];
          #pragma unroll
          for (int i = 0; i < 4; i++){
            float av = a[i];
            mean[i] = (dm*av + sb[i])*inv;
            float vv = (dm*av*av + 2.f*av*sb[i] + sq[i])*inv - mean[i]*mean[i];
            sd[i] = sqrtf(fmaxf(vv, 0.f) + 1e-5f);
            lo[i] = deg > 0 ? av + mn[i] : 0.f;
            hi[i] = deg > 0 ? av + mx[i] : 0.f;
          }
          *(uint2*)(st)       = make_uint2(pk(mean[0],mean[1]), pk(mean[2],mean[3]));
          *(uint2*)(st +  80) = make_uint2(pk(lo[0],lo[1]),     pk(lo[2],lo[3]));
          *(uint2*)(st + 160) = make_uint2(pk(hi[0],hi[1]),     pk(hi[2],hi[3]));
          *(uint2*)(st + 240) = make_uint2(pk(sd[0],sd[1]),     pk(sd[2],sd[3]));
        } else {
          uint2 z = make_uint2(0u, 0u);
          *(uint2*)(st)       = z;
          *(uint2*)(st +  80) = z;
          *(uint2*)(st + 160) = z;
          *(uint2*)(st + 240) = z;
        }
      }
    }
#undef ACC2
  }

  // ---- stage h rows into As k<80 (f32->bf16); zero pad k in [400,416)
  {
    const int grow = row0 + ra;
    #pragma unroll
    for (int c = 0; c < 7; c++){
      int kg = ka0 + c*64;
      if (kg < 80){
        uint4 pa; pa.x = pa.y = pa.z = pa.w = 0u;
        if (grow < NN){
          const float* ap = h + grow*80 + kg;
          float4 f0 = *(const float4*)ap;
          float4 f1 = *(const float4*)(ap + 4);
          pa.x = pk(f0.x, f0.y); pa.y = pk(f0.z, f0.w);
          pa.z = pk(f1.x, f1.y); pa.w = pk(f1.z, f1.w);
        }
        ldsst16(&As[ra*AST + kg], pa);
      } else if (kg >= 400 && kg < 416){
        uint4 z; z.x = z.y = z.z = z.w = 0u;
        ldsst16(&As[ra*AST + kg], z);
      }
    }
  }

  // ---- per-lane tiled-B base pointers (OOB cols clamped; their acc unused)
  const bf16* bp[4];
  #pragma unroll
  for (int ct = 0; ct < 4; ct++){
    int col = wc + ct*16 + m16;
    if (col >= 240) col = 0;
    bp[ct] = Bt + col*32 + q*8;
  }
  __syncthreads();   // full A panel (stats + h + pad) ready

  f32x4 acc[2][4] = {};

  // ---- barrier-free K loop: direct-global B frags (contiguous 1KB/wave/frag)
  #pragma unroll
  for (int ks = 0; ks < NKT; ks++){
    bf16x8 bfv[4], af[2];
    #pragma unroll
    for (int ct = 0; ct < 4; ct++)
      bfv[ct] = *(const bf16x8*)(bp[ct] + ks*7680);
    #pragma unroll
    for (int rt = 0; rt < 2; rt++)
      af[rt] = ldsld8(&As[(rt*16 + m16)*AST + ks*32 + q*8]);
    #pragma unroll
    for (int rt = 0; rt < 2; rt++)
      #pragma unroll
      for (int ct = 0; ct < 4; ct++)
        acc[rt][ct] = __builtin_amdgcn_mfma_f32_16x16x32_bf16(af[rt], bfv[ct], acc[rt][ct], 0, 0, 0);
  }
  __syncthreads();   // all waves done reading As before eL overwrite

  // ---- epilogue: stage P|Q|R in eL
  #pragma unroll
  for (int rt = 0; rt < 2; rt++){
    #pragma unroll
    for (int ct = 0; ct < 4; ct++){
      int col = wc + ct*16 + m16;
      if (col >= 240) continue;
      #pragma unroll
      for (int rr = 0; rr < 4; rr++){
        int r = rt*16 + q*4 + rr;
        eL[r*248 + col] = f2b(acc[rt][ct][rr]);
      }
    }
  }
  __syncthreads();

  // ---- combine -> h_new; write global f32 + LDS bf16 panel
  #pragma unroll
  for (int i = 0; i < 10; i++){
    int idx = tid + i*256;
    int r = idx / 80, c = idx - r*80;
    int row = row0 + r;
    if (row < NN){
      float P = b2f(eL[r*248 + c]);
      float Q = b2f(eL[r*248 + 80 + c]);
      float R = b2f(eL[r*248 + 160 + c]);
      float o = P + scf[row]*Q + invf[row]*R + bias2v[c];
      float hn = hp[row*80 + c] + fmaxf(o, 0.f);
      hp[row*80 + c] = hn;
      if (Bt1n) hA[r*100 + c] = f2b(hn);
    } else if (Bt1n && idx < 32*80){
      hA[r*100 + c] = f2b(0.f);   // tail rows: defined values for mini-GEMM
    }
  }
  if (Bt1n && tid < 128){
    // zero pad k in [80,96)
    int r = tid >> 2, off = 80 + (tid & 3)*4;
    *(uint2*)&hA[r*100 + off] = make_uint2(0u, 0u);
  }
  __syncthreads();

  // ---- mini-GEMM: U = h_new @ Bt1[next] (tiled-B, barrier-free)
  if (Bt1n){
    const bf16* bp1[4];
    #pragma unroll
    for (int ct = 0; ct < 4; ct++){
      int col = wc + ct*16 + m16;
      if (col >= 160) col = 0;
      bp1[ct] = Bt1n + col*32 + q*8;
    }
    f32x4 acc2[2][4] = {};
    #pragma unroll
    for (int ks = 0; ks < 3; ks++){
      bf16x8 bfv[4], af[2];
      #pragma unroll
      for (int ct = 0; ct < 4; ct++)
        bfv[ct] = *(const bf16x8*)(bp1[ct] + ks*5120);
      #pragma unroll
      for (int rt = 0; rt < 2; rt++)
        af[rt] = ldsld8((const short*)hA + (rt*16 + m16)*100 + ks*32 + q*8);
      #pragma unroll
      for (int rt = 0; rt < 2; rt++)
        #pragma unroll
        for (int ct = 0; ct < 4; ct++)
          acc2[rt][ct] = __builtin_amdgcn_mfma_f32_16x16x32_bf16(af[rt], bfv[ct], acc2[rt][ct], 0, 0, 0);
    }
    #pragma unroll
    for (int rt = 0; rt < 2; rt++){
      #pragma unroll
      for (int rr = 0; rr < 4; rr++){
        int row = row0 + rt*16 + q*4 + rr;
        if (row >= NN) continue;
        #pragma unroll
        for (int ct = 0; ct < 4; ct++){
          int col = wc + ct*16 + m16;
          if (col >= 160) continue;
          float v = acc2[rt][ct][rr] + bias1n[col];
          if (col < 80) Uaw[row*80 + col]      = f2b(v);
          else          Ubw[row*80 + col - 80] = f2b(v);
        }
      }
    }
  }
}

// ------------------------------------------------------------------ fused mean-pool + head
__global__ __launch_bounds__(128) void k_poolmlp(const float* __restrict__ h,
                        const int* __restrict__ batch,
                        const void* __restrict__ mlpW, const void* __restrict__ mlpb,
                        const int* __restrict__ flag, void* __restrict__ outp){
  __shared__ float sred[128];
  __shared__ int sb[2];
  int g = blockIdx.x;
  int t = threadIdx.x;
  if (t < 2){
    int target = g + t;
    int lo = 0, hi = NN;
    while (lo < hi){ int mid = (lo + hi) >> 1; if (batch[mid] < target) lo = mid + 1; else hi = mid; }
    sb[t] = lo;
  }
  __syncthreads();
  int lo = sb[0], hi = sb[1];
  float s = 0.f;
  if (t < 80)
    for (int n = lo; n < hi; n++) s += h[n*80 + t];
  int fl = flag[0];
  float wv = (t < 80) ? rdw(mlpW, t, fl) : 0.f;
  sred[t] = s * wv;
  __syncthreads();
  for (int off = 64; off > 0; off >>= 1){
    if (t < off) sred[t] += sred[t + off];
    __syncthreads();
  }
  if (t == 0){
    float cnt = (float)(hi - lo); if (cnt < 1.f) cnt = 1.f;
    float r = sred[0]/cnt + rdw(mlpb, 0, fl);
    if (fl) ((float*)outp)[g] = r;
    else    ((bf16*)outp)[g] = f2b(r);
  }
}

// ------------------------------------------------------------------ launch
extern "C" void kernel_launch(void* const* d_in, const int* in_sizes, int n_in,
                              void* d_out, int out_size, void* d_ws, size_t ws_size,
                              hipStream_t stream)
{
  const int*  x     = (const int*) d_in[0];
  const int*  ei    = (const int*) d_in[1];
  const int*  batch = (const int*) d_in[2];
  const void* avgp  = d_in[3];
  const void* aemb  = d_in[4];
  const void* preW  = d_in[5];
  const void* preb  = d_in[6];
  const void* postW = d_in[7];
  const void* postb = d_in[8];
  const void* linW  = d_in[9];
  const void* linb  = d_in[10];
  const void* bng   = d_in[11];
  const void* bnb   = d_in[12];
  const void* bnm   = d_in[13];
  const void* bnv   = d_in[14];
  const void* mlpW  = d_in[15];
  const void* mlpb  = d_in[16];

  char* w = (char*)d_ws;
  int*   flag   = (int*)  (w + 400000);       //       256  (zeroed)
  int*   rowptr = (int*)  (w + 401280);       //   200,064
  int*   colidx = (int*)  (w + 601344);       // 3,200,000
  float* scf    = (float*)(w + 3801344);      //   200,000
  float* invf   = (float*)(w + 4001344);      //   200,000
  float* bias1  = (float*)(w + 4201344);      //     2,560
  float* bias2  = (float*)(w + 4203904);      //     1,280
  bf16*  Btl    = (bf16*) (w + 4205184);      //    61,440
  bf16*  Bt1    = (bf16*) (w + 4266624);      //   122,880  (tiled layout)
  bf16*  Bt2    = (bf16*) (w + 4389504);      //   798,720  (tiled layout)
  float* h      = (float*)(w + 5188224);      // 16,000,000  f32 [N,80]
  bf16*  UaA    = (bf16*) (w + 21188224);     //  8,000,000  bf16 [N,80]
  bf16*  UbA    = (bf16*) (w + 29188224);     //  8,000,000  bf16 [N,80]
  bf16*  UaB    = (bf16*) (w + 45188224);     //  8,000,000  (ping-pong, ex-agg)
  bf16*  UbB    = (bf16*) (w + 53188224);     //  8,000,000
  // pre-loop overlays (consumed before layer 0):
  bf16*  pwb    = (bf16*) (w + 61188224);     //   665,600
  float* Wf     = (float*)(w + 61853824);     // 1,331,200
  int* staging  = (int*)  (w + 63185024);     // 3,200,000
  int* chunkcnt = (int*)  (w + 66385024);     //   613,088  [NCH][NBUCK]
  int* btotal   = (int*)  (w + 66998112);     //     3,128
  int* bbase    = (int*)  (w + 67001240);     //     3,136  (NBUCK+1)
  // total 77,188,224 B (end 67,004,376)

  k_zero <<<1, 256, 0, stream>>>(flag, 64);
  k_probe<<<16, 256, 0, stream>>>(aemb, flag);

  // atomic-free CSR build
  k_hist <<<NCH, 256, 0, stream>>>(ei, chunkcnt);
  k_cscan<<<NBUCK, 256, 0, stream>>>(chunkcnt, btotal);
  k_bscan<<<1, 256, 0, stream>>>(btotal, bbase);
  k_place<<<NCH, 256, 0, stream>>>(ei, chunkcnt, bbase, staging);

  k_prep_all<<<1662, 256, 0, stream>>>(preW, preb, postW, postb, linW, linb,
                                       bng, bnb, bnm, bnv, flag,
                                       pwb, Btl, Bt1, bias1, bias2);

  // Wf[i] = postW[i](bf16) @ Btl[i]^T   (f32 out)
  k_mgemm<0,1,96,100><<<dim3(17,1,4), 256, 0, stream>>>(
      pwb, 80, 80, nullptr, 0, 0,
      Btl, 96, 80, nullptr, Wf, nullptr, 80, 1040,
      166400, 15360, 332800);
  k_prep_Bt2<<<(4*240*416 + 255)/256, 256, 0, stream>>>(Wf, Bt2);

  k_atom <<<(NN*10 + 255)/256, 256, 0, stream>>>(x, aemb, flag, h);

  // fused rowptr/scf/invf + counting-sorted colidx
  k_csr<<<NBUCK, 256, 0, stream>>>(staging, bbase, avgp, flag, rowptr, scf, invf, colidx);

  const int gx2 = (NN + 31)/32;   // 1563
  // layer-0 GEMM1 (subsequent layers' GEMM1 are fused into k_g2's tail)
  k_g1<<<dim3(gx2,1,1), 256, 0, stream>>>(h, Bt1, bias1, UaA, UbA);
  for (int i = 0; i < 4; i++){
    const bf16* Uar = (i & 1) ? UaB : UaA;
    const bf16* Ubr = (i & 1) ? UbB : UbA;
    bf16* Uaw = (i & 1) ? UaA : UaB;
    bf16* Ubw = (i & 1) ? UbA : UbB;
    const bf16* nBt1 = (i < 3) ? (Bt1 + (i+1)*15360) : nullptr;
    const float* nb1 = (i < 3) ? (bias1 + (i+1)*160) : bias1;
    k_g2<<<dim3(gx2,1,1), 256, 0, stream>>>(
        h, Uar, Ubr, rowptr, colidx,
        Bt2 + i*99840, bias2 + i*80, scf, invf, h,
        nBt1, nb1, Uaw, Ubw);
  }

  k_poolmlp<<<NGR, 128, 0, stream>>>(h, batch, mlpW, mlpb, flag, d_out);
}

// Round 17
// 488.205 us; speedup vs baseline: 1.0725x; 1.0292x over previous
//
#include <hip/hip_runtime.h>
#include <hip/hip_bf16.h>

#define NN 50000
#define NE 800000
#define FD 80
#define NGR 1024
#define NF 9

// bucketed CSR sort (atomic-free counting sort)
#define BSH 6
#define NBUCK ((NN + 63) >> 6)     // 782 node-buckets of 64
#define CSH 12
#define NCH ((NE + 4095) >> 12)    // 196 edge-chunks of 4096
#define BCAP 2048

using bf16 = __hip_bfloat16;
typedef __attribute__((ext_vector_type(8))) short bf16x8;
typedef __attribute__((ext_vector_type(4))) float f32x4;

static __device__ __forceinline__ float b2f(bf16 v){ return __bfloat162float(v); }
static __device__ __forceinline__ bf16 f2b(float v){ return __float2bfloat16(v); }
static __device__ __forceinline__ float rdw(const void* p, int i, int fl){
  return fl ? ((const float*)p)[i] : b2f(((const bf16*)p)[i]);
}
static __device__ __forceinline__ unsigned pk(float a, float b){
  bf16 x = f2b(a), y = f2b(b);
  return (unsigned)*(unsigned short*)&x | ((unsigned)*(unsigned short*)&y << 16);
}
static __device__ __forceinline__ float us2f(unsigned short u){
  return __uint_as_float((unsigned)u << 16);
}
// 8B-granule LDS access (strides are 8B- but not 16B-aligned)
static __device__ __forceinline__ bf16x8 ldsld8(const short* p){
  union { bf16x8 v; uint2 u[2]; } r;
  r.u[0] = *(const uint2*)(p);
  r.u[1] = *(const uint2*)(p + 4);
  return r.v;
}
static __device__ __forceinline__ void ldsst16(short* p, uint4 v){
  *(uint2*)(p)     = make_uint2(v.x, v.y);
  *(uint2*)(p + 4) = make_uint2(v.z, v.w);
}

// ------------------------------------------------------------------ utility
__global__ void k_zero(int* __restrict__ p, int n){
  int t = blockIdx.x*256 + threadIdx.x;
  if (t < n) p[t] = 0;
}

__global__ void k_probe(const void* __restrict__ emb, int* __restrict__ flag){
  int t = blockIdx.x*256 + threadIdx.x;
  float v = b2f(((const bf16*)emb)[t]);
  if (!(fabsf(v) < 1e4f)) atomicOr(flag, 1);
}

// ------------------------------------------------------------------ fused weight prep
// Bt1/Bt2 in K-step-major FRAGMENT-TILED layout (r12 win): one wave's MFMA
// B-frag load is a contiguous 1KB segment (direct-global, no LDS staging).
__global__ __launch_bounds__(256) void k_prep_all(
    const void* __restrict__ preW, const void* __restrict__ preb,
    const void* __restrict__ postW, const void* __restrict__ postb,
    const void* __restrict__ linW, const void* __restrict__ linb,
    const void* __restrict__ bng, const void* __restrict__ bnb,
    const void* __restrict__ bnm, const void* __restrict__ bnv,
    const int* __restrict__ flag,
    bf16* __restrict__ pwb, bf16* __restrict__ Btl, bf16* __restrict__ Bt1,
    float* __restrict__ bias1, float* __restrict__ bias2)
{
  int fl = flag[0];
  int b = blockIdx.x;
  if (b < 1300){
    int t = b*256 + threadIdx.x;
    pwb[t] = f2b(rdw(postW, t, fl));
  } else if (b < 1420){
    int t = (b - 1300)*256 + threadIdx.x;
    int j = t % 96, c = (t/96) % 80, i = t/(96*80);
    float v = 0.f;
    if (j < 80){
      float gs = rdw(bng, i*80 + c, fl) * rsqrtf(rdw(bnv, i*80 + c, fl) + 1e-5f);
      v = rdw(linW, i*6400 + j*80 + c, fl) * gs;
    }
    Btl[t] = f2b(v);
  } else if (b < 1660){
    int t = (b - 1420)*256 + threadIdx.x;
    int k = t % 96, c = (t/96) % 160, i = t/(96*160);
    float v = 0.f;
    if (k < 80)
      v = (c < 80) ? rdw(preW, (i*160 + k)*80 + c, fl)
                   : rdw(preW, (i*160 + 80 + k)*80 + (c - 80), fl);
    int of = ((k >> 5)*160 + c)*32 + (k & 31);
    Bt1[i*15360 + of] = f2b(v);
    if (k == 0) bias1[i*160 + c] = (c < 80) ? rdw(preb, i*80 + c, fl) : 0.f;
  } else {
    int t = (b - 1660)*256 + threadIdx.x;
    if (t >= 4*80) return;
    int i = t / 80, f = t - i*80;
    float s = 0.f;
    for (int j = 0; j < 80; j++)
      s += rdw(postb, i*80 + j, fl) * rdw(linW, (i*80 + j)*80 + f, fl);
    s += rdw(linb, t, fl);
    float gs = rdw(bng, t, fl) * rsqrtf(rdw(bnv, t, fl) + 1e-5f);
    bias2[t] = (s - rdw(bnm, t, fl)) * gs + rdw(bnb, t, fl);
  }
}

// Bt2 in fragment-tiled layout: element (c,k) at ks*240*32 + c*32 + (k&31).
__global__ void k_prep_Bt2(const float* __restrict__ Wf, bf16* __restrict__ Bt2){
  int t = blockIdx.x*256 + threadIdx.x;
  if (t >= 4*240*416) return;
  int k = t % 416;
  int c = (t/416) % 240;
  int i = t/(416*240);
  float v = 0.f;
  if (k < 400){
    int blk = c/80, f = c - blk*80;
    if (blk == 0) v = Wf[(i*1040 + k)*80 + f];
    else if (k >= 80){
      int row = (blk == 1 ? 400 : 720) + (k - 80);
      v = Wf[(i*1040 + row)*80 + f];
    }
  }
  int of = (k >> 5)*7680 + c*32 + (k & 31);
  Bt2[i*99840 + of] = f2b(v);
}

// ------------------------------------------------------------------ graph prep
__global__ void k_atom(const int* __restrict__ x, const void* __restrict__ emb,
                       const int* __restrict__ flag, float* __restrict__ h){
  int fl = flag[0];
  int gid = blockIdx.x*256 + threadIdx.x;
  if (gid >= NN*10) return;
  int n = gid / 10, fb = gid - n*10;
  int f0 = fb*8;
  int xr[NF];
  #pragma unroll
  for (int c = 0; c < NF; c++) xr[c] = x[n*NF + c];
  float s[8] = {0.f,0.f,0.f,0.f,0.f,0.f,0.f,0.f};
  if (fl){
    #pragma unroll
    for (int c = 0; c < NF; c++){
      const float* ep = (const float*)emb + (c*119 + xr[c])*80 + f0;
      float4 a = *(const float4*)ep, b = *(const float4*)(ep + 4);
      s[0]+=a.x; s[1]+=a.y; s[2]+=a.z; s[3]+=a.w;
      s[4]+=b.x; s[5]+=b.y; s[6]+=b.z; s[7]+=b.w;
    }
  } else {
    #pragma unroll
    for (int c = 0; c < NF; c++){
      const bf16* ep = (const bf16*)emb + (c*119 + xr[c])*80 + f0;
      uint4 u = *(const uint4*)ep;
      s[0]+=__uint_as_float(u.x<<16); s[1]+=__uint_as_float(u.x&0xffff0000u);
      s[2]+=__uint_as_float(u.y<<16); s[3]+=__uint_as_float(u.y&0xffff0000u);
      s[4]+=__uint_as_float(u.z<<16); s[5]+=__uint_as_float(u.z&0xffff0000u);
      s[6]+=__uint_as_float(u.w<<16); s[7]+=__uint_as_float(u.w&0xffff0000u);
    }
  }
  float* hp = h + n*80 + f0;
  *(float4*)hp       = make_float4(s[0],s[1],s[2],s[3]);
  *(float4*)(hp + 4) = make_float4(s[4],s[5],s[6],s[7]);
}

// ---- atomic-free CSR build: hist -> cscan -> bscan -> place -> csr ----

__global__ __launch_bounds__(256) void k_hist(const int* __restrict__ ei,
                                              int* __restrict__ chunkcnt){
  __shared__ int hist[NBUCK];
  int c = blockIdx.x, t = threadIdx.x;
  for (int i = t; i < NBUCK; i += 256) hist[i] = 0;
  __syncthreads();
  #pragma unroll
  for (int j = 0; j < 16; j++){
    int e = (c << CSH) + j*256 + t;
    if (e < NE) atomicAdd(&hist[ei[NE + e] >> BSH], 1);
  }
  __syncthreads();
  for (int i = t; i < NBUCK; i += 256) chunkcnt[c*NBUCK + i] = hist[i];
}

__global__ __launch_bounds__(256) void k_cscan(int* __restrict__ chunkcnt,
                                               int* __restrict__ btotal){
  __shared__ int buf[256];
  int b = blockIdx.x, t = threadIdx.x;
  int v[4]; int s = 0;
  #pragma unroll
  for (int j = 0; j < 4; j++){
    int c = t*4 + j;
    v[j] = (c < NCH) ? chunkcnt[c*NBUCK + b] : 0;
    s += v[j];
  }
  buf[t] = s;
  __syncthreads();
  for (int off = 1; off < 256; off <<= 1){
    int xv = (t >= off) ? buf[t - off] : 0;
    __syncthreads();
    buf[t] += xv;
    __syncthreads();
  }
  int excl = buf[t] - s;
  #pragma unroll
  for (int j = 0; j < 4; j++){
    int c = t*4 + j;
    if (c < NCH){ chunkcnt[c*NBUCK + b] = excl; excl += v[j]; }
  }
  if (t == 255) btotal[b] = buf[255];
}

__global__ __launch_bounds__(256) void k_bscan(const int* __restrict__ btotal,
                                               int* __restrict__ bbase){
  __shared__ int buf[256];
  int t = threadIdx.x;
  int v[4]; int s = 0;
  #pragma unroll
  for (int j = 0; j < 4; j++){
    int c = t*4 + j;
    v[j] = (c < NBUCK) ? btotal[c] : 0;
    s += v[j];
  }
  buf[t] = s;
  __syncthreads();
  for (int off = 1; off < 256; off <<= 1){
    int xv = (t >= off) ? buf[t - off] : 0;
    __syncthreads();
    buf[t] += xv;
    __syncthreads();
  }
  int excl = buf[t] - s;
  #pragma unroll
  for (int j = 0; j < 4; j++){
    int c = t*4 + j;
    if (c < NBUCK){ bbase[c] = excl; excl += v[j]; }
  }
  if (t == 255) bbase[NBUCK] = buf[255];
}

__global__ __launch_bounds__(256) void k_place(const int* __restrict__ ei,
                        const int* __restrict__ chunkcnt, const int* __restrict__ bbase,
                        int* __restrict__ staging){
  __shared__ int basep[NBUCK];
  __shared__ int cur[NBUCK];
  int c = blockIdx.x, t = threadIdx.x;
  for (int i = t; i < NBUCK; i += 256){
    basep[i] = chunkcnt[c*NBUCK + i] + bbase[i];
    cur[i] = 0;
  }
  __syncthreads();
  #pragma unroll
  for (int j = 0; j < 16; j++){
    int e = (c << CSH) + j*256 + t;
    if (e < NE){
      int d = ei[NE + e], s = ei[e];
      int b = d >> BSH;
      int r = atomicAdd(&cur[b], 1);
      staging[basep[b] + r] = (s << BSH) | (d & 63);
    }
  }
}

__global__ __launch_bounds__(256) void k_csr(const int* __restrict__ staging,
                        const int* __restrict__ bbase, const void* __restrict__ avgp,
                        const int* __restrict__ flag, int* __restrict__ rowptr,
                        float* __restrict__ scf, float* __restrict__ invf,
                        int* __restrict__ colidx){
  __shared__ int lcnt[64], lrp[64], lcur[64];
  __shared__ int colbuf[BCAP];
  int b = blockIdx.x, t = threadIdx.x;
  int base = bbase[b];
  int cnt  = bbase[b+1] - base;
  if (t < 64){ lcnt[t] = 0; lcur[t] = 0; }
  __syncthreads();
  for (int i = t; i < cnt; i += 256)
    atomicAdd(&lcnt[staging[base + i] & 63], 1);
  __syncthreads();
  if (t < 64) lrp[t] = lcnt[t];
  __syncthreads();
  for (int off = 1; off < 64; off <<= 1){
    int xv = (t < 64 && t >= off) ? lrp[t - off] : 0;
    __syncthreads();
    if (t < 64) lrp[t] += xv;
    __syncthreads();
  }
  int n0 = b << BSH;
  if (t < 64){
    int ex = lrp[t] - lcnt[t];
    lrp[t] = ex;
    int n = n0 + t;
    if (n < NN){
      rowptr[n] = base + ex;
      float degc = (float)(lcnt[t] > 0 ? lcnt[t] : 1);
      float logd = logf(degc + 1.f);
      float avg = rdw(avgp, 0, flag[0]);
      scf[n] = logd / avg;
      invf[n] = avg / logd;
    }
  }
  if (b == 0 && t == 0) rowptr[NN] = NE;
  __syncthreads();
  if (cnt <= BCAP){
    for (int i = t; i < cnt; i += 256){
      int v = staging[base + i];
      int l = v & 63;
      int pos = lrp[l] + atomicAdd(&lcur[l], 1);
      colbuf[pos] = v >> BSH;
    }
    __syncthreads();
    for (int i = t; i < cnt; i += 256)
      colidx[base + i] = colbuf[i];
  } else {
    for (int i = t; i < cnt; i += 256){
      int v = staging[base + i];
      int l = v & 63;
      int pos = lrp[l] + atomicAdd(&lcur[l], 1);
      colidx[base + pos] = v >> BSH;
    }
  }
}

// ------------------------------------------------------------------ MFMA GEMM (r4 structure; Wf only)
template<int AF32, int OUTMODE, int K_, int AST>
__global__ __launch_bounds__(256) void k_mgemm(
    const void* __restrict__ A1p, int s1, int KA,
    const bf16* __restrict__ A2, int s2, int KB,
    const bf16* __restrict__ Btp, int Bts, int Ncols,
    const float* __restrict__ bias,
    void* __restrict__ Cbase, void* __restrict__ Cp2, int Cstride, int M,
    int lA1b, int lBtb, int lCb)
{
  const void* A1 = (const char*)A1p + (size_t)blockIdx.z*lA1b;
  const bf16* Bt = (const bf16*)((const char*)Btp + (size_t)blockIdx.z*lBtb);
  void* Cp = (char*)Cbase + (size_t)blockIdx.z*lCb;

  constexpr int NKT = K_ / 32;
  __shared__ short As[64*AST];
  __shared__ short Bs[256*44];

  const int tid = threadIdx.x;
  const int row0 = blockIdx.x * 64;
  const int wave = tid >> 6, lane = tid & 63;
  const int wc = wave * 64;
  const int m16 = lane & 15, q = lane >> 4;

  const int ra = tid >> 2, ka = (tid & 3) * 8;
  const int cb = tid >> 2, kb = (tid & 3) * 8;

  f32x4 acc[4][4] = {};
  uint4 pb[4];

#define LOADB(k0_) { int kgb = (k0_) + kb;                                     \
    _Pragma("unroll")                                                          \
    for (int j = 0; j < 4; j++){                                               \
      int col = cb + j*64;                                                     \
      pb[j].x = pb[j].y = pb[j].z = pb[j].w = 0u;                              \
      if (col < Ncols) pb[j] = *(const uint4*)(Bt + col*Bts + kgb);            \
    } }

  LOADB(0);

  {
    const int grow = row0 + ra;
    uint4 tA[NKT];
    #pragma unroll
    for (int c = 0; c < NKT; c++){
      int kg = c*32 + ka;
      uint4 pa; pa.x = pa.y = pa.z = pa.w = 0u;
      if (grow < M){
        if (kg < KA){
          if (AF32){
            const float* ap = (const float*)A1 + grow*s1 + kg;
            float4 f0 = *(const float4*)ap;
            float4 f1 = *(const float4*)(ap + 4);
            pa.x = pk(f0.x, f0.y); pa.y = pk(f0.z, f0.w);
            pa.z = pk(f1.x, f1.y); pa.w = pk(f1.z, f1.w);
          } else {
            pa = *(const uint4*)((const bf16*)A1 + grow*s1 + kg);
          }
        } else if (kg - KA < KB){
          pa = *(const uint4*)(A2 + grow*s2 + (kg - KA));
        }
      }
      tA[c] = pa;
    }
    #pragma unroll
    for (int c = 0; c < NKT; c++)
      ldsst16(&As[ra*AST + c*32 + ka], tA[c]);
  }
  __syncthreads();

  #pragma unroll
  for (int ks = 0; ks < NKT; ks++){
    #pragma unroll
    for (int j = 0; j < 4; j++)
      ldsst16(&Bs[(cb + j*64)*44 + kb], pb[j]);
    __syncthreads();

    if (ks + 1 < NKT) LOADB((ks + 1)*32);

    bf16x8 af[4], bfv[4];
    #pragma unroll
    for (int rt = 0; rt < 4; rt++)
      af[rt] = ldsld8(&As[(rt*16 + m16)*AST + ks*32 + q*8]);
    #pragma unroll
    for (int ct = 0; ct < 4; ct++)
      bfv[ct] = ldsld8(&Bs[(wc + ct*16 + m16)*44 + q*8]);
    #pragma unroll
    for (int rt = 0; rt < 4; rt++)
      #pragma unroll
      for (int ct = 0; ct < 4; ct++)
        acc[rt][ct] = __builtin_amdgcn_mfma_f32_16x16x32_bf16(af[rt], bfv[ct], acc[rt][ct], 0, 0, 0);
    __syncthreads();
  }
#undef LOADB

  #pragma unroll
  for (int rt = 0; rt < 4; rt++){
    #pragma unroll
    for (int rr = 0; rr < 4; rr++){
      int row = row0 + rt*16 + q*4 + rr;
      if (row >= M) continue;
      #pragma unroll
      for (int ct = 0; ct < 4; ct++){
        int col = wc + ct*16 + m16;
        if (col >= Ncols) continue;
        float v = acc[rt][ct][rr] + (bias ? bias[col] : 0.f);
        if (OUTMODE == 1) ((float*)Cp)[row*Cstride + col] = v;
        else {
          if (col < 80) ((bf16*)Cp )[row*80 + col]      = f2b(v);
          else          ((bf16*)Cp2)[row*80 + col - 80] = f2b(v);
        }
      }
    }
  }
}

// ------------------------------------------------------------------ layer-0 GEMM1 (direct tiled-B, barrier-free)
__global__ __launch_bounds__(256) void k_g1(
    const float* __restrict__ h, const bf16* __restrict__ Bt1t,
    const float* __restrict__ bias1v,
    bf16* __restrict__ Ua, bf16* __restrict__ Ub)
{
  __shared__ short hA[32*100];   // 6,400 B
  const int tid = threadIdx.x;
  const int row0 = blockIdx.x * 32;
  const int wave = tid >> 6, lane = tid & 63;
  const int wc = wave * 64;
  const int m16 = lane & 15, q = lane >> 4;
  const int ra = tid >> 3, ka0 = (tid & 7) * 8;

  // stage h rows (f32->bf16); zero pad k in [80,96)
  {
    int grow = row0 + ra;
    #pragma unroll
    for (int c = 0; c < 2; c++){
      int kg = ka0 + c*64;
      if (kg < 96){
        uint4 pa; pa.x = pa.y = pa.z = pa.w = 0u;
        if (kg < 80 && grow < NN){
          const float* ap = h + grow*80 + kg;
          float4 f0 = *(const float4*)ap, f1 = *(const float4*)(ap + 4);
          pa.x = pk(f0.x, f0.y); pa.y = pk(f0.z, f0.w);
          pa.z = pk(f1.x, f1.y); pa.w = pk(f1.z, f1.w);
        }
        ldsst16(&hA[ra*100 + kg], pa);
      }
    }
  }
  __syncthreads();

  const bf16* bp1[4];
  #pragma unroll
  for (int ct = 0; ct < 4; ct++){
    int col = wc + ct*16 + m16;
    if (col >= 160) col = 0;
    bp1[ct] = Bt1t + col*32 + q*8;
  }
  f32x4 acc[2][4] = {};
  #pragma unroll
  for (int ks = 0; ks < 3; ks++){
    bf16x8 bfv[4], af[2];
    #pragma unroll
    for (int ct = 0; ct < 4; ct++)
      bfv[ct] = *(const bf16x8*)(bp1[ct] + ks*5120);
    #pragma unroll
    for (int rt = 0; rt < 2; rt++)
      af[rt] = ldsld8(&hA[(rt*16 + m16)*100 + ks*32 + q*8]);
    #pragma unroll
    for (int rt = 0; rt < 2; rt++)
      #pragma unroll
      for (int ct = 0; ct < 4; ct++)
        acc[rt][ct] = __builtin_amdgcn_mfma_f32_16x16x32_bf16(af[rt], bfv[ct], acc[rt][ct], 0, 0, 0);
  }
  #pragma unroll
  for (int rt = 0; rt < 2; rt++){
    #pragma unroll
    for (int rr = 0; rr < 4; rr++){
      int row = row0 + rt*16 + q*4 + rr;
      if (row >= NN) continue;
      #pragma unroll
      for (int ct = 0; ct < 4; ct++){
        int col = wc + ct*16 + m16;
        if (col >= 160) continue;
        float v = acc[rt][ct][rr] + bias1v[col];
        if (col < 80) Ua[row*80 + col]      = f2b(v);
        else          Ub[row*80 + col - 80] = f2b(v);
      }
    }
  }
}

// ------------------------------------------------------------------ fully-fused layer: agg + GEMM2 + epilogue + next GEMM1
// r16 form (502.5us best), plus: the staging phase keeps its f32 h values in
// REGISTERS (hs[16], statically indexed) and the epilogue is re-mapped to the
// staging thread layout -> the 16MB/layer global h re-read (and its
// dependent-load latency) disappears. Semantics identical: blocks own
// disjoint h rows; hp unchanged between kernel start and epilogue.
__global__ __launch_bounds__(256) void k_g2(
    const float* __restrict__ h,
    const bf16* __restrict__ Uar, const bf16* __restrict__ Ubr,
    const int* __restrict__ rowptr, const int* __restrict__ colidx,
    const bf16* __restrict__ Bt, const float* __restrict__ bias2v,
    const float* __restrict__ scf, const float* __restrict__ invf,
    float* __restrict__ hp,
    const bf16* __restrict__ Bt1n, const float* __restrict__ bias1n,
    bf16* __restrict__ Uaw, bf16* __restrict__ Ubw)
{
  constexpr int AST = 420, NKT = 13;
  __shared__ short As[32*AST];   // 26,880 B
  bf16* eL = (bf16*)As;                 // epilogue staging 32x248 (15,872 B)
  bf16* hA = (bf16*)(As + 8192);        // h_new panel 32x100 (bytes 16,384..22,784)

  const int tid = threadIdx.x;
  const int row0 = blockIdx.x * 32;
  const int wave = tid >> 6, lane = tid & 63;
  const int wc = wave * 64;
  const int m16 = lane & 15, q = lane >> 4;
  const int ra = tid >> 3;           // 32 rows, 8 threads/row
  const int ka0 = (tid & 7) * 8;     // chunk start; stride 64 shorts

  // ---- fused PNA aggregation FIRST: 3 sub-rounds x (12 nodes x 20 thr x 4 feat)
  //      gathers issue at kernel start; h streaming below overlaps their latency
  {
    int s20 = tid / 20;            // node slot within sub-round (inactive >= 12)
    int fo = (tid - s20*20) * 4;   // feature offset
#define ACC2(w, o) { \
    float b0 = __uint_as_float((w) << 16); \
    float b1 = __uint_as_float((w) & 0xffff0000u); \
    sb[o] += b0; sq[o] += b0*b0; mn[o] = fminf(mn[o],b0); mx[o] = fmaxf(mx[o],b0); \
    sb[o+1] += b1; sq[o+1] += b1*b1; mn[o+1] = fminf(mn[o+1],b1); mx[o+1] = fmaxf(mx[o+1],b1); }
    #pragma unroll 1
    for (int rnd = 0; rnd < 3; rnd++){
      int slot = rnd*12 + s20;
      if (s20 < 12 && slot < 32){
        int n = row0 + slot;
        short* st = &As[slot*AST + 80 + fo];
        if (n < NN){
          int rs = rowptr[n], re = rowptr[n+1];   // broadcast within node group (L1)
          int deg = re - rs;
          float a[4];
          {
            uint2 ua = *(const uint2*)(Uar + n*80 + fo);
            a[0] = __uint_as_float(ua.x << 16);
            a[1] = __uint_as_float(ua.x & 0xffff0000u);
            a[2] = __uint_as_float(ua.y << 16);
            a[3] = __uint_as_float(ua.y & 0xffff0000u);
          }
          float sb[4] = {0.f,0.f,0.f,0.f}, sq[4] = {0.f,0.f,0.f,0.f};
          float mn[4] = {1e30f,1e30f,1e30f,1e30f}, mx[4] = {-1e30f,-1e30f,-1e30f,-1e30f};
          for (int e = rs; e < re; e += 16){
            int cnt = re - e; if (cnt > 16) cnt = 16;
            int sx[16];
            #pragma unroll
            for (int j = 0; j < 16; j++) sx[j] = (j < cnt) ? colidx[e + j] : sx[0];
            uint2 u[16];
            #pragma unroll
            for (int j = 0; j < 16; j++) u[j] = *(const uint2*)(Ubr + sx[j]*80 + fo);
            #pragma unroll
            for (int j = 0; j < 16; j++){
              if (j < cnt){ ACC2(u[j].x, 0); ACC2(u[j].y, 2); }
            }
          }
          float degc = (float)(deg > 0 ? deg : 1);
          float inv = 1.f/degc;
          float dm = (float)deg;
          float mean[4], lo[4], hi[4], sd[4];
          #pragma unroll
          for (int i = 0; i < 4; i++){
            float av = a[i];
            mean[i] = (dm*av + sb[i])*inv;
            float vv = (dm*av*av + 2.f*av*sb[i] + sq[i])*inv - mean[i]*mean[i];
            sd[i] = sqrtf(fmaxf(vv, 0.f) + 1e-5f);
            lo[i] = deg > 0 ? av + mn[i] : 0.f;
            hi[i] = deg > 0 ? av + mx[i] : 0.f;
          }
          *(uint2*)(st)       = make_uint2(pk(mean[0],mean[1]), pk(mean[2],mean[3]));
          *(uint2*)(st +  80) = make_uint2(pk(lo[0],lo[1]),     pk(lo[2],lo[3]));
          *(uint2*)(st + 160) = make_uint2(pk(hi[0],hi[1]),     pk(hi[2],hi[3]));
          *(uint2*)(st + 240) = make_uint2(pk(sd[0],sd[1]),     pk(sd[2],sd[3]));
        } else {
          uint2 z = make_uint2(0u, 0u);
          *(uint2*)(st)       = z;
          *(uint2*)(st +  80) = z;
          *(uint2*)(st + 160) = z;
          *(uint2*)(st + 240) = z;
        }
      }
    }
#undef ACC2
  }

  // ---- stage h rows into As k<80 (f32->bf16), KEEPING f32 in registers;
  //      zero pad k in [400,416) (threads ka0 in {16,24})
  float hs[16];
  {
    const int grow = row0 + ra;
    // chunk 0: kg = ka0 (always < 64 < 80)
    {
      uint4 pa; pa.x = pa.y = pa.z = pa.w = 0u;
      if (grow < NN){
        const float* ap = h + grow*80 + ka0;
        float4 f0 = *(const float4*)ap, f1 = *(const float4*)(ap + 4);
        pa.x = pk(f0.x, f0.y); pa.y = pk(f0.z, f0.w);
        pa.z = pk(f1.x, f1.y); pa.w = pk(f1.z, f1.w);
        hs[0]=f0.x; hs[1]=f0.y; hs[2]=f0.z; hs[3]=f0.w;
        hs[4]=f1.x; hs[5]=f1.y; hs[6]=f1.z; hs[7]=f1.w;
      }
      ldsst16(&As[ra*AST + ka0], pa);
    }
    // chunk 1: kg = ka0+64, valid (<80) iff ka0 < 16
    if (ka0 < 16){
      uint4 pa; pa.x = pa.y = pa.z = pa.w = 0u;
      if (grow < NN){
        const float* ap = h + grow*80 + ka0 + 64;
        float4 f0 = *(const float4*)ap, f1 = *(const float4*)(ap + 4);
        pa.x = pk(f0.x, f0.y); pa.y = pk(f0.z, f0.w);
        pa.z = pk(f1.x, f1.y); pa.w = pk(f1.z, f1.w);
        hs[8]=f0.x;  hs[9]=f0.y;  hs[10]=f0.z; hs[11]=f0.w;
        hs[12]=f1.x; hs[13]=f1.y; hs[14]=f1.z; hs[15]=f1.w;
      }
      ldsst16(&As[ra*AST + ka0 + 64], pa);
    }
    // pad zero: kg in [400,416) handled by ka0 == 16 (->400) and 24 (->408)
    if (ka0 == 16 || ka0 == 24){
      uint4 z; z.x = z.y = z.z = z.w = 0u;
      ldsst16(&As[ra*AST + 384 + ka0], z);
    }
  }

  // ---- per-lane tiled-B base pointers (OOB cols clamped; their acc unused)
  const bf16* bp[4];
  #pragma unroll
  for (int ct = 0; ct < 4; ct++){
    int col = wc + ct*16 + m16;
    if (col >= 240) col = 0;
    bp[ct] = Bt + col*32 + q*8;
  }
  __syncthreads();   // full A panel (stats + h + pad) ready

  f32x4 acc[2][4] = {};

  // ---- barrier-free K loop: direct-global B frags (contiguous 1KB/wave/frag)
  #pragma unroll
  for (int ks = 0; ks < NKT; ks++){
    bf16x8 bfv[4], af[2];
    #pragma unroll
    for (int ct = 0; ct < 4; ct++)
      bfv[ct] = *(const bf16x8*)(bp[ct] + ks*7680);
    #pragma unroll
    for (int rt = 0; rt < 2; rt++)
      af[rt] = ldsld8(&As[(rt*16 + m16)*AST + ks*32 + q*8]);
    #pragma unroll
    for (int rt = 0; rt < 2; rt++)
      #pragma unroll
      for (int ct = 0; ct < 4; ct++)
        acc[rt][ct] = __builtin_amdgcn_mfma_f32_16x16x32_bf16(af[rt], bfv[ct], acc[rt][ct], 0, 0, 0);
  }
  __syncthreads();   // all waves done reading As before eL overwrite

  // ---- epilogue: stage P|Q|R in eL
  #pragma unroll
  for (int rt = 0; rt < 2; rt++){
    #pragma unroll
    for (int ct = 0; ct < 4; ct++){
      int col = wc + ct*16 + m16;
      if (col >= 240) continue;
      #pragma unroll
      for (int rr = 0; rr < 4; rr++){
        int r = rt*16 + q*4 + rr;
        eL[r*248 + col] = f2b(acc[rt][ct][rr]);
      }
    }
  }
  __syncthreads();

  // ---- combine -> h_new (f32 h from registers; no global re-read);
  //      staging-thread layout: (row ra, cols ka0..ka0+8 [+64..72 if ka0<16])
  {
    int row = row0 + ra;
    if (row < NN){
      float sc = scf[row], iv = invf[row];
      const short* eS = (const short*)eL;
      #pragma unroll
      for (int half = 0; half < 2; half++){
        if (half == 1 && ka0 >= 16) continue;
        int cbase = ka0 + half*64;
        bf16x8 Pv = ldsld8(eS + ra*248 + cbase);
        bf16x8 Qv = ldsld8(eS + ra*248 + 80 + cbase);
        bf16x8 Rv = ldsld8(eS + ra*248 + 160 + cbase);
        float hn[8];
        #pragma unroll
        for (int j = 0; j < 8; j++){
          float P = us2f((unsigned short)Pv[j]);
          float Q = us2f((unsigned short)Qv[j]);
          float R = us2f((unsigned short)Rv[j]);
          float o = P + sc*Q + iv*R + bias2v[cbase + j];
          hn[j] = hs[half*8 + j] + fmaxf(o, 0.f);
        }
        float* op = hp + row*80 + cbase;
        *(float4*)op       = make_float4(hn[0], hn[1], hn[2], hn[3]);
        *(float4*)(op + 4) = make_float4(hn[4], hn[5], hn[6], hn[7]);
        if (Bt1n){
          *(uint2*)&hA[ra*100 + cbase]     = make_uint2(pk(hn[0],hn[1]), pk(hn[2],hn[3]));
          *(uint2*)&hA[ra*100 + cbase + 4] = make_uint2(pk(hn[4],hn[5]), pk(hn[6],hn[7]));
        }
      }
    } else if (Bt1n){
      uint2 z = make_uint2(0u, 0u);
      *(uint2*)&hA[ra*100 + ka0]     = z;
      *(uint2*)&hA[ra*100 + ka0 + 4] = z;
      if (ka0 < 16){
        *(uint2*)&hA[ra*100 + ka0 + 64] = z;
        *(uint2*)&hA[ra*100 + ka0 + 68] = z;
      }
    }
  }
  if (Bt1n && tid < 128){
    // zero pad k in [80,96)
    int r = tid >> 2, off = 80 + (tid & 3)*4;
    *(uint2*)&hA[r*100 + off] = make_uint2(0u, 0u);
  }
  __syncthreads();

  // ---- mini-GEMM: U = h_new @ Bt1[next] (tiled-B, barrier-free)
  if (Bt1n){
    const bf16* bp1[4];
    #pragma unroll
    for (int ct = 0; ct < 4; ct++){
      int col = wc + ct*16 + m16;
      if (col >= 160) col = 0;
      bp1[ct] = Bt1n + col*32 + q*8;
    }
    f32x4 acc2[2][4] = {};
    #pragma unroll
    for (int ks = 0; ks < 3; ks++){
      bf16x8 bfv[4], af[2];
      #pragma unroll
      for (int ct = 0; ct < 4; ct++)
        bfv[ct] = *(const bf16x8*)(bp1[ct] + ks*5120);
      #pragma unroll
      for (int rt = 0; rt < 2; rt++)
        af[rt] = ldsld8((const short*)hA + (rt*16 + m16)*100 + ks*32 + q*8);
      #pragma unroll
      for (int rt = 0; rt < 2; rt++)
        #pragma unroll
        for (int ct = 0; ct < 4; ct++)
          acc2[rt][ct] = __builtin_amdgcn_mfma_f32_16x16x32_bf16(af[rt], bfv[ct], acc2[rt][ct], 0, 0, 0);
    }
    #pragma unroll
    for (int rt = 0; rt < 2; rt++){
      #pragma unroll
      for (int rr = 0; rr < 4; rr++){
        int row = row0 + rt*16 + q*4 + rr;
        if (row >= NN) continue;
        #pragma unroll
        for (int ct = 0; ct < 4; ct++){
          int col = wc + ct*16 + m16;
          if (col >= 160) continue;
          float v = acc2[rt][ct][rr] + bias1n[col];
          if (col < 80) Uaw[row*80 + col]      = f2b(v);
          else          Ubw[row*80 + col - 80] = f2b(v);
        }
      }
    }
  }
}

// ------------------------------------------------------------------ fused mean-pool + head
__global__ __launch_bounds__(128) void k_poolmlp(const float* __restrict__ h,
                        const int* __restrict__ batch,
                        const void* __restrict__ mlpW, const void* __restrict__ mlpb,
                        const int* __restrict__ flag, void* __restrict__ outp){
  __shared__ float sred[128];
  __shared__ int sb[2];
  int g = blockIdx.x;
  int t = threadIdx.x;
  if (t < 2){
    int target = g + t;
    int lo = 0, hi = NN;
    while (lo < hi){ int mid = (lo + hi) >> 1; if (batch[mid] < target) lo = mid + 1; else hi = mid; }
    sb[t] = lo;
  }
  __syncthreads();
  int lo = sb[0], hi = sb[1];
  float s = 0.f;
  if (t < 80)
    for (int n = lo; n < hi; n++) s += h[n*80 + t];
  int fl = flag[0];
  float wv = (t < 80) ? rdw(mlpW, t, fl) : 0.f;
  sred[t] = s * wv;
  __syncthreads();
  for (int off = 64; off > 0; off >>= 1){
    if (t < off) sred[t] += sred[t + off];
    __syncthreads();
  }
  if (t == 0){
    float cnt = (float)(hi - lo); if (cnt < 1.f) cnt = 1.f;
    float r = sred[0]/cnt + rdw(mlpb, 0, fl);
    if (fl) ((float*)outp)[g] = r;
    else    ((bf16*)outp)[g] = f2b(r);
  }
}

// ------------------------------------------------------------------ launch
extern "C" void kernel_launch(void* const* d_in, const int* in_sizes, int n_in,
                              void* d_out, int out_size, void* d_ws, size_t ws_size,
                              hipStream_t stream)
{
  const int*  x     = (const int*) d_in[0];
  const int*  ei    = (const int*) d_in[1];
  const int*  batch = (const int*) d_in[2];
  const void* avgp  = d_in[3];
  const void* aemb  = d_in[4];
  const void* preW  = d_in[5];
  const void* preb  = d_in[6];
  const void* postW = d_in[7];
  const void* postb = d_in[8];
  const void* linW  = d_in[9];
  const void* linb  = d_in[10];
  const void* bng   = d_in[11];
  const void* bnb   = d_in[12];
  const void* bnm   = d_in[13];
  const void* bnv   = d_in[14];
  const void* mlpW  = d_in[15];
  const void* mlpb  = d_in[16];

  char* w = (char*)d_ws;
  int*   flag   = (int*)  (w + 400000);       //       256  (zeroed)
  int*   rowptr = (int*)  (w + 401280);       //   200,064
  int*   colidx = (int*)  (w + 601344);       // 3,200,000
  float* scf    = (float*)(w + 3801344);      //   200,000
  float* invf   = (float*)(w + 4001344);      //   200,000
  float* bias1  = (float*)(w + 4201344);      //     2,560
  float* bias2  = (float*)(w + 4203904);      //     1,280
  bf16*  Btl    = (bf16*) (w + 4205184);      //    61,440
  bf16*  Bt1    = (bf16*) (w + 4266624);      //   122,880  (tiled layout)
  bf16*  Bt2    = (bf16*) (w + 4389504);      //   798,720  (tiled layout)
  float* h      = (float*)(w + 5188224);      // 16,000,000  f32 [N,80]
  bf16*  UaA    = (bf16*) (w + 21188224);     //  8,000,000  bf16 [N,80]
  bf16*  UbA    = (bf16*) (w + 29188224);     //  8,000,000  bf16 [N,80]
  bf16*  UaB    = (bf16*) (w + 45188224);     //  8,000,000  (ping-pong, ex-agg)
  bf16*  UbB    = (bf16*) (w + 53188224);     //  8,000,000
  // pre-loop overlays (consumed before layer 0):
  bf16*  pwb    = (bf16*) (w + 61188224);     //   665,600
  float* Wf     = (float*)(w + 61853824);     // 1,331,200
  int* staging  = (int*)  (w + 63185024);     // 3,200,000
  int* chunkcnt = (int*)  (w + 66385024);     //   613,088  [NCH][NBUCK]
  int* btotal   = (int*)  (w + 66998112);     //     3,128
  int* bbase    = (int*)  (w + 67001240);     //     3,136  (NBUCK+1)
  // total 77,188,224 B (end 67,004,376)

  k_zero <<<1, 256, 0, stream>>>(flag, 64);
  k_probe<<<16, 256, 0, stream>>>(aemb, flag);

  // atomic-free CSR build
  k_hist <<<NCH, 256, 0, stream>>>(ei, chunkcnt);
  k_cscan<<<NBUCK, 256, 0, stream>>>(chunkcnt, btotal);
  k_bscan<<<1, 256, 0, stream>>>(btotal, bbase);
  k_place<<<NCH, 256, 0, stream>>>(ei, chunkcnt, bbase, staging);

  k_prep_all<<<1662, 256, 0, stream>>>(preW, preb, postW, postb, linW, linb,
                                       bng, bnb, bnm, bnv, flag,
                                       pwb, Btl, Bt1, bias1, bias2);

  // Wf[i] = postW[i](bf16) @ Btl[i]^T   (f32 out)
  k_mgemm<0,1,96,100><<<dim3(17,1,4), 256, 0, stream>>>(
      pwb, 80, 80, nullptr, 0, 0,
      Btl, 96, 80, nullptr, Wf, nullptr, 80, 1040,
      166400, 15360, 332800);
  k_prep_Bt2<<<(4*240*416 + 255)/256, 256, 0, stream>>>(Wf, Bt2);

  k_atom <<<(NN*10 + 255)/256, 256, 0, stream>>>(x, aemb, flag, h);

  // fused rowptr/scf/invf + counting-sorted colidx
  k_csr<<<NBUCK, 256, 0, stream>>>(staging, bbase, avgp, flag, rowptr, scf, invf, colidx);

  const int gx2 = (NN + 31)/32;   // 1563
  // layer-0 GEMM1 (subsequent layers' GEMM1 are fused into k_g2's tail)
  k_g1<<<dim3(gx2,1,1), 256, 0, stream>>>(h, Bt1, bias1, UaA, UbA);
  for (int i = 0; i < 4; i++){
    const bf16* Uar = (i & 1) ? UaB : UaA;
    const bf16* Ubr = (i & 1) ? UbB : UbA;
    bf16* Uaw = (i & 1) ? UaA : UaB;
    bf16* Ubw = (i & 1) ? UbA : UbB;
    const bf16* nBt1 = (i < 3) ? (Bt1 + (i+1)*15360) : nullptr;
    const float* nb1 = (i < 3) ? (bias1 + (i+1)*160) : bias1;
    k_g2<<<dim3(gx2,1,1), 256, 0, stream>>>(
        h, Uar, Ubr, rowptr, colidx,
        Bt2 + i*99840, bias2 + i*80, scf, invf, h,
        nBt1, nb1, Uaw, Ubw);
  }

  k_poolmlp<<<NGR, 128, 0, stream>>>(h, batch, mlpW, mlpb, flag, d_out);
}